// Round 1
// baseline (3274.203 us; speedup 1.0000x reference)
//
#include <hip/hip_runtime.h>
#include <math.h>

// Problem constants (fixed by the reference setup_inputs)
#define BB 16      // batch
#define NN 24564   // anchors
#define CC 81      // classes
#define KK 50      // max per-class NMS picks
#define MT 200     // max total
#define CAP 13312  // candidate capacity per (b,c): mean ~12.1k, sd ~78 -> 15 sigma

// ---------------------------------------------------------------------------
// Kernel 1: per-anchor decode + background mask
// ---------------------------------------------------------------------------
__global__ __launch_bounds__(256) void k_decode(
    const float* __restrict__ deltas, const float* __restrict__ labels,
    const float* __restrict__ priors, float4* __restrict__ boxes,
    unsigned char* __restrict__ bg)
{
    int i = blockIdx.x * 256 + threadIdx.x;   // i = b*NN + n
    if (i >= BB * NN) return;
    int n = i % NN;

    // argmax over 81 classes, first-index-wins (matches jnp.argmax)
    const float* lab = labels + (size_t)i * CC;
    float best = lab[0];
    int bi = 0;
    for (int c = 1; c < CC; ++c) {
        float v = lab[c];
        if (v > best) { best = v; bi = c; }
    }
    bg[i] = (bi == 0) ? 1 : 0;

    // decode, bit-matching numpy op order (no FMA contraction)
    float4 pr = ((const float4*)priors)[n];   // y1 x1 y2 x2
    float ph  = __fsub_rn(pr.z, pr.x);
    float pw  = __fsub_rn(pr.w, pr.y);
    float pcy = __fadd_rn(pr.x, __fmul_rn(0.5f, ph));
    float pcx = __fadd_rn(pr.y, __fmul_rn(0.5f, pw));
    float4 dl = ((const float4*)deltas)[i];
    float d0 = __fmul_rn(dl.x, 0.1f);
    float d1 = __fmul_rn(dl.y, 0.1f);
    float d2 = __fmul_rn(dl.z, 0.2f);
    float d3 = __fmul_rn(dl.w, 0.2f);
    float cy = __fadd_rn(__fmul_rn(d0, ph), pcy);
    float cx = __fadd_rn(__fmul_rn(d1, pw), pcx);
    float h  = __fmul_rn(expf(d2), ph);
    float w  = __fmul_rn(expf(d3), pw);
    float h2 = __fmul_rn(h, 0.5f);
    float w2 = __fmul_rn(w, 0.5f);
    float y1 = fminf(fmaxf(__fsub_rn(cy, h2), 0.0f), 1.0f);
    float x1 = fminf(fmaxf(__fsub_rn(cx, w2), 0.0f), 1.0f);
    float y2 = fminf(fmaxf(__fadd_rn(cy, h2), 0.0f), 1.0f);
    float x2 = fminf(fmaxf(__fadd_rn(cx, w2), 0.0f), 1.0f);
    boxes[i] = make_float4(y1, x1, y2, x2);
}

// ---------------------------------------------------------------------------
// Kernel 2: per-(b,c) greedy NMS. One block per (b,c).
// Candidates (score > 0.5, not background) compacted into LDS.
// ---------------------------------------------------------------------------
__global__ __launch_bounds__(1024) void k_nms(
    const float* __restrict__ labels, const float4* __restrict__ boxes,
    const unsigned char* __restrict__ bg,
    float* __restrict__ out_s, int* __restrict__ out_i)
{
    __shared__ float s_sc[CAP];
    __shared__ unsigned short s_id[CAP];
    __shared__ int s_cnt;
    __shared__ float r_v[16];
    __shared__ int   r_i[16];
    __shared__ int   r_p[16];

    int bc = blockIdx.x;
    int b = bc / CC, c = bc % CC;
    int tid = threadIdx.x;
    if (tid == 0) s_cnt = 0;
    __syncthreads();

    // compact candidates: masked score > SCORE_THR
    const float* lab_b = labels + (size_t)b * NN * CC + c;
    const unsigned char* bg_b = bg + (size_t)b * NN;
    for (int n = tid; n < NN; n += 1024) {
        float v = lab_b[(size_t)n * CC];
        if (v > 0.5f && !bg_b[n]) {
            int p = atomicAdd(&s_cnt, 1);
            if (p < CAP) { s_sc[p] = v; s_id[p] = (unsigned short)n; }
        }
    }
    __syncthreads();
    int cnt = min(s_cnt, CAP);

    const float4* bx_b = boxes + (size_t)b * NN;
    float* os = out_s + (size_t)bc * KK;
    int*   oi = out_i + (size_t)bc * KK;
    for (int k = tid; k < KK; k += 1024) { os[k] = 0.0f; oi[k] = 0; }

    for (int k = 0; k < KK; ++k) {
        // lexicographic argmax: (score desc, anchor idx asc) == jnp.argmax
        float bv = -1.0f; int bi = NN; int bp = 0;
        for (int i2 = tid; i2 < cnt; i2 += 1024) {
            float v = s_sc[i2];
            int id = (int)s_id[i2];
            if (v > bv || (v == bv && id < bi)) { bv = v; bi = id; bp = i2; }
        }
        for (int off = 32; off > 0; off >>= 1) {
            float ov = __shfl_down(bv, off);
            int oid  = __shfl_down(bi, off);
            int op   = __shfl_down(bp, off);
            if (ov > bv || (ov == bv && oid < bi)) { bv = ov; bi = oid; bp = op; }
        }
        int wid = tid >> 6;
        if ((tid & 63) == 0) { r_v[wid] = bv; r_i[wid] = bi; r_p[wid] = bp; }
        __syncthreads();
        if (tid == 0) {
            for (int wv = 1; wv < 16; ++wv) {
                if (r_v[wv] > bv || (r_v[wv] == bv && r_i[wv] < bi)) {
                    bv = r_v[wv]; bi = r_i[wv]; bp = r_p[wv];
                }
            }
            r_v[0] = bv; r_i[0] = bi; r_p[0] = bp;
        }
        __syncthreads();
        bv = r_v[0]; bi = r_i[0]; bp = r_p[0];
        if (bv <= 0.5f) break;   // all further picks invalid -> outputs stay 0

        if (tid == 0) { os[k] = bv; oi[k] = bi; s_sc[bp] = 0.0f; }

        // suppression sweep (exact numpy op order; FMA-free)
        float4 jb = bx_b[bi];
        float a0 = __fmul_rn(__fsub_rn(jb.z, jb.x), __fsub_rn(jb.w, jb.y));
        for (int i2 = tid; i2 < cnt; i2 += 1024) {
            float v = s_sc[i2];
            if (v == 0.0f) continue;
            float4 cb = bx_b[(int)s_id[i2]];
            float iy1 = fmaxf(jb.x, cb.x);
            float ix1 = fmaxf(jb.y, cb.y);
            float iy2 = fminf(jb.z, cb.z);
            float ix2 = fminf(jb.w, cb.w);
            float ih = fmaxf(__fsub_rn(iy2, iy1), 0.0f);
            float iw = fmaxf(__fsub_rn(ix2, ix1), 0.0f);
            float inter = __fmul_rn(ih, iw);
            float a1 = __fmul_rn(__fsub_rn(cb.z, cb.x), __fsub_rn(cb.w, cb.y));
            float den = __fadd_rn(__fsub_rn(__fadd_rn(a0, a1), inter), 1e-8f);
            float iou = __fdiv_rn(inter, den);
            if (iou > 0.5f) s_sc[i2] = 0.0f;
        }
        __syncthreads();
    }
}

// ---------------------------------------------------------------------------
// Kernel 3: per-batch stable top-200 + output assembly. One block per batch.
// ---------------------------------------------------------------------------
__global__ __launch_bounds__(256) void k_topk(
    const float* __restrict__ nms_s, const int* __restrict__ nms_i,
    const float4* __restrict__ boxes, float* __restrict__ out)
{
    __shared__ float s_sc[CC * KK];
    __shared__ float r_v[4];
    __shared__ int   r_p[4];
    int b = blockIdx.x, tid = threadIdx.x;
    for (int i = tid; i < CC * KK; i += 256) s_sc[i] = nms_s[(size_t)b * CC * KK + i];
    __syncthreads();

    float4* ob  = (float4*)out;            // (B,200,4)
    float*  osc = out + BB * MT * 4;       // (B,200)
    float*  ocl = osc + BB * MT;           // (B,200)
    float*  ovc = ocl + BB * MT;           // (B,)
    int vcount = 0;

    for (int r = 0; r < MT; ++r) {
        // stable argmax: (score desc, flat pos asc) == jax top_k tie rule
        float bv = -2.0f; int bp = CC * KK;
        for (int i = tid; i < CC * KK; i += 256) {
            float v = s_sc[i];
            if (v > bv || (v == bv && i < bp)) { bv = v; bp = i; }
        }
        for (int off = 32; off > 0; off >>= 1) {
            float ov = __shfl_down(bv, off);
            int op   = __shfl_down(bp, off);
            if (ov > bv || (ov == bv && op < bp)) { bv = ov; bp = op; }
        }
        if ((tid & 63) == 0) { r_v[tid >> 6] = bv; r_p[tid >> 6] = bp; }
        __syncthreads();
        if (tid == 0) {
            for (int wv = 1; wv < 4; ++wv) {
                if (r_v[wv] > bv || (r_v[wv] == bv && r_p[wv] < bp)) {
                    bv = r_v[wv]; bp = r_p[wv];
                }
            }
            s_sc[bp] = -1.0f;  // sentinel; real scores are >= 0
            bool valid = bv > 0.0f;
            float4 bb = make_float4(0.f, 0.f, 0.f, 0.f);
            float cls = 0.0f;
            if (valid) {
                int aidx = nms_i[(size_t)b * CC * KK + bp];
                bb = boxes[(size_t)b * NN + aidx];
                cls = (float)(bp / KK);
            }
            ob[(size_t)b * MT + r]  = bb;
            osc[(size_t)b * MT + r] = bv;
            ocl[(size_t)b * MT + r] = cls;
            vcount += valid ? 1 : 0;
        }
        __syncthreads();
    }
    if (tid == 0) ovc[b] = (float)vcount;
}

// ---------------------------------------------------------------------------
extern "C" void kernel_launch(void* const* d_in, const int* in_sizes, int n_in,
                              void* d_out, int out_size, void* d_ws, size_t ws_size,
                              hipStream_t stream)
{
    const float* deltas = (const float*)d_in[0];   // (B,N,4)
    const float* labels = (const float*)d_in[1];   // (B,N,C)
    const float* priors = (const float*)d_in[2];   // (N,4)
    float* out = (float*)d_out;

    char* ws = (char*)d_ws;
    float4* boxes      = (float4*)ws;                                  // B*N*16 bytes
    size_t off = (size_t)BB * NN * 16;
    unsigned char* bg  = (unsigned char*)(ws + off);                   // B*N bytes
    off += (size_t)BB * NN;
    float* nms_s       = (float*)(ws + off);                           // B*C*K floats
    off += (size_t)BB * CC * KK * 4;
    int* nms_i         = (int*)(ws + off);                             // B*C*K ints

    k_decode<<<(BB * NN + 255) / 256, 256, 0, stream>>>(deltas, labels, priors, boxes, bg);
    k_nms<<<BB * CC, 1024, 0, stream>>>(labels, (const float4*)boxes, bg, nms_s, nms_i);
    k_topk<<<BB, 256, 0, stream>>>(nms_s, nms_i, (const float4*)boxes, out);
}

// Round 2
// 855.998 us; speedup vs baseline: 3.8250x; 3.8250x over previous
//
#include <hip/hip_runtime.h>
#include <math.h>

#define BB 16
#define NN 24564
#define CC 81
#define KK 50
#define MT 200
#define NROWS (BB * NN)        // 393024 = 64 * 6141 exactly
#define CAND_CAP 1024          // per-(b,c) global candidate list capacity
#define T1 0.98f               // tier-1 score threshold (expected ~485/class)
#define TIER_W 0.02f
#define FCAP 2048              // LDS sort capacity (also fallback tier cap)

typedef unsigned long long u64;
typedef unsigned int u32;

__device__ __forceinline__ u64 pack_cand(float s, int n) {
    return ((u64)__float_as_uint(s) << 32) | (u32)(~(u32)n);
}

// descending bitonic sort of P u64 keys in LDS, NT threads
template <int P, int NT>
__device__ __forceinline__ void bitonic_desc(u64* a, int tid) {
    for (int k = 2; k <= P; k <<= 1) {
        for (int j = k >> 1; j > 0; j >>= 1) {
            for (int i = tid; i < P; i += NT) {
                int l = i ^ j;
                if (l > i) {
                    u64 x = a[i], y = a[l];
                    bool sw = (i & k) ? (x > y) : (x < y);
                    if (sw) { a[i] = y; a[l] = x; }
                }
            }
            __syncthreads();
        }
    }
}

// ---------------------------------------------------------------------------
// Kernel 1: fused decode + bg + candidate filter.
// Block = 128 threads (2 waves). Each wave owns 32 rows: cooperative
// float4-coalesced load of 32*81 floats into LDS, then 2 lanes/row compute
// rowmax (bg), scatter candidates > T1, and lane h==0 decodes the box.
// ---------------------------------------------------------------------------
__global__ __launch_bounds__(128) void k_decode_filter(
    const float* __restrict__ deltas, const float* __restrict__ labels,
    const float* __restrict__ priors, float4* __restrict__ boxes,
    unsigned char* __restrict__ bg, int* __restrict__ cnt_g,
    u64* __restrict__ cand_g)
{
    __shared__ float4 lab4[2][648];   // 2 waves x 32 rows x 81 floats
    int tid = threadIdx.x;
    int w = tid >> 6, lane = tid & 63;
    int r0 = blockIdx.x * 64 + w * 32;            // first row of this wave
    const float4* src = (const float4*)(labels + (size_t)r0 * CC);
    #pragma unroll
    for (int j = 0; j < 11; ++j) {
        int idx = lane + 64 * j;
        if (idx < 648) lab4[w][idx] = src[idx];
    }
    __syncthreads();

    int row = lane & 31, h = lane >> 5;
    int r = r0 + row;
    int b = r / NN, n = r - b * NN;
    const float* L = (const float*)lab4[w] + row * CC;

    // rowmax over split class ranges, combine across the lane pair
    int c0 = h ? 41 : 0, c1 = h ? 81 : 41;
    float m = -1.0f;
    for (int c = c0; c < c1; ++c) m = fmaxf(m, L[c]);
    float rowmax = fmaxf(m, __shfl_xor(m, 32));
    bool isbg = (L[0] >= rowmax);     // argmax == 0  (first-index tie rule)
    if (h == 0) bg[r] = isbg ? 1 : 0;

    // candidate scatter
    if (!isbg) {
        for (int c = c0; c < c1; ++c) {
            float v = L[c];
            if (v > T1) {
                int bc = b * CC + c;
                int p = atomicAdd(&cnt_g[bc], 1);
                if (p < CAND_CAP) cand_g[(size_t)bc * CAND_CAP + p] = pack_cand(v, n);
            }
        }
    }

    // box decode (exact numpy op order, FMA-free), lane h==0 only
    if (h == 0) {
        float4 pr = ((const float4*)priors)[n];
        float ph  = __fsub_rn(pr.z, pr.x);
        float pw  = __fsub_rn(pr.w, pr.y);
        float pcy = __fadd_rn(pr.x, __fmul_rn(0.5f, ph));
        float pcx = __fadd_rn(pr.y, __fmul_rn(0.5f, pw));
        float4 dl = ((const float4*)deltas)[r];
        float d0 = __fmul_rn(dl.x, 0.1f);
        float d1 = __fmul_rn(dl.y, 0.1f);
        float d2 = __fmul_rn(dl.z, 0.2f);
        float d3 = __fmul_rn(dl.w, 0.2f);
        float cy = __fadd_rn(__fmul_rn(d0, ph), pcy);
        float cx = __fadd_rn(__fmul_rn(d1, pw), pcx);
        float hh = __fmul_rn(expf(d2), ph);
        float ww = __fmul_rn(expf(d3), pw);
        float h2 = __fmul_rn(hh, 0.5f);
        float w2 = __fmul_rn(ww, 0.5f);
        float y1 = fminf(fmaxf(__fsub_rn(cy, h2), 0.0f), 1.0f);
        float x1 = fminf(fmaxf(__fsub_rn(cx, w2), 0.0f), 1.0f);
        float y2 = fminf(fmaxf(__fadd_rn(cy, h2), 0.0f), 1.0f);
        float x2 = fminf(fmaxf(__fadd_rn(cx, w2), 0.0f), 1.0f);
        boxes[r] = make_float4(y1, x1, y2, x2);
    }
}

// ---------------------------------------------------------------------------
// Kernel 2: per-(b,c) sorted-scan greedy NMS. Block = 256 threads.
// Tier 1 from prebuilt global list; exact fallback tiers re-scan the class
// column in descending 0.02-wide score bands (statistically never runs).
// ---------------------------------------------------------------------------
__global__ __launch_bounds__(256) void k_nms(
    const float* __restrict__ labels, const unsigned char* __restrict__ bg,
    const float4* __restrict__ boxes, const int* __restrict__ cnt_g,
    const u64* __restrict__ cand_g,
    float* __restrict__ out_s, int* __restrict__ out_i)
{
    __shared__ u64 arr[FCAP];
    __shared__ float ks[KK];
    __shared__ int   ki[KK];
    __shared__ int s_kept, s_cnt;

    int bc = blockIdx.x, tid = threadIdx.x;
    int b = bc / CC, c = bc - b * CC;
    const float4* bxb = boxes + (size_t)b * NN;

    int gcnt = cnt_g[bc];
    bool ovf = gcnt > CAND_CAP;       // tier-1 list incomplete -> full fallback
    int cnt0 = ovf ? 0 : gcnt;
    for (int i = tid; i < FCAP; i += 256)
        arr[i] = (i < cnt0) ? cand_g[(size_t)bc * CAND_CAP + i] : 0ull;
    if (tid == 0) { s_kept = 0; s_cnt = cnt0; }
    __syncthreads();

    float4 kb = make_float4(0.f, 0.f, 0.f, 0.f);  // lane's kept box (wave 0)
    float  ka = 0.0f;                              // its area
    float hi = ovf ? 1.0001f : T1;    // upper bound of next fallback band
    bool first = !ovf;

    while (true) {
        if (!first) {
            if (s_kept >= KK || hi <= 0.5f) break;
            float lo = fmaxf(hi - TIER_W, 0.5f);
            if (tid == 0) s_cnt = 0;
            __syncthreads();
            const float* lab = labels + (size_t)b * NN * CC + c;
            const unsigned char* bgb = bg + (size_t)b * NN;
            for (int n = tid; n < NN; n += 256) {
                float v = lab[(size_t)n * CC];
                if (v > lo && v <= hi && v > 0.5f && !bgb[n]) {
                    int p = atomicAdd(&s_cnt, 1);
                    if (p < FCAP) arr[p] = pack_cand(v, n);
                }
            }
            __syncthreads();
            int cc2 = min(s_cnt, FCAP);
            for (int i = tid; i < FCAP; i += 256)
                if (i >= cc2) arr[i] = 0ull;
            hi = lo;
        }
        first = false;
        __syncthreads();

        bitonic_desc<FCAP, 256>(arr, tid);   // ends with __syncthreads

        int cnt = min(s_cnt, FCAP);
        if (tid < 64) {                      // wave 0: serial greedy scan
            int kept = s_kept;
            for (int i = 0; i < cnt; ++i) {
                u64 key = arr[i];
                float sc = __uint_as_float((u32)(key >> 32));
                int n = (int)(~(u32)key);
                float4 cb = bxb[n];
                float a1 = __fmul_rn(__fsub_rn(cb.z, cb.x), __fsub_rn(cb.w, cb.y));
                bool sup = false;
                if (tid < kept) {
                    float iy1 = fmaxf(kb.x, cb.x);
                    float ix1 = fmaxf(kb.y, cb.y);
                    float iy2 = fminf(kb.z, cb.z);
                    float ix2 = fminf(kb.w, cb.w);
                    float ih = fmaxf(__fsub_rn(iy2, iy1), 0.0f);
                    float iw = fmaxf(__fsub_rn(ix2, ix1), 0.0f);
                    float inter = __fmul_rn(ih, iw);
                    float den = __fadd_rn(__fsub_rn(__fadd_rn(ka, a1), inter), 1e-8f);
                    sup = __fdiv_rn(inter, den) > 0.5f;
                }
                if (__ballot(sup) == 0ull) {
                    if (tid == kept) { kb = cb; ka = a1; }
                    if (tid == 0)    { ks[kept] = sc; ki[kept] = n; }
                    ++kept;
                    if (kept == KK) break;
                }
            }
            if (tid == 0) s_kept = kept;
        }
        __syncthreads();
    }

    int kept = min(s_kept, KK);
    for (int k = tid; k < KK; k += 256) {
        out_s[(size_t)bc * KK + k] = (k < kept) ? ks[k] : 0.0f;
        out_i[(size_t)bc * KK + k] = (k < kept) ? ki[k] : 0;
    }
}

// ---------------------------------------------------------------------------
// Kernel 3: per-batch bitonic top-200 (stable) + output assembly.
// ---------------------------------------------------------------------------
__global__ __launch_bounds__(1024) void k_topk(
    const float* __restrict__ nms_s, const int* __restrict__ nms_i,
    const float4* __restrict__ boxes, float* __restrict__ out)
{
    __shared__ u64 arr[4096];
    __shared__ int s_vc;
    int b = blockIdx.x, tid = threadIdx.x;
    for (int i = tid; i < 4096; i += 1024) {
        u64 v = 0ull;
        if (i < CC * KK) {
            float s = nms_s[(size_t)b * CC * KK + i];
            v = ((u64)__float_as_uint(s) << 32) | (u32)(~(u32)i);
        }
        arr[i] = v;
    }
    if (tid == 0) s_vc = 0;
    __syncthreads();

    bitonic_desc<4096, 1024>(arr, tid);

    if (tid < MT) {
        u64 key = arr[tid];
        float sc = __uint_as_float((u32)(key >> 32));
        int fp = (int)(~(u32)key);
        bool valid = sc > 0.0f;
        float4 bb = make_float4(0.f, 0.f, 0.f, 0.f);
        float cls = 0.0f;
        if (valid) {
            int aidx = nms_i[(size_t)b * CC * KK + fp];
            bb = boxes[(size_t)b * NN + aidx];
            cls = (float)(fp / KK);
        }
        ((float4*)out)[(size_t)b * MT + tid] = bb;
        out[(size_t)BB * MT * 4 + (size_t)b * MT + tid] = sc;
        out[(size_t)BB * MT * 5 + (size_t)b * MT + tid] = cls;
        if (valid) atomicAdd(&s_vc, 1);
    }
    __syncthreads();
    if (tid == 0) out[(size_t)BB * MT * 6 + b] = (float)s_vc;
}

// ---------------------------------------------------------------------------
extern "C" void kernel_launch(void* const* d_in, const int* in_sizes, int n_in,
                              void* d_out, int out_size, void* d_ws, size_t ws_size,
                              hipStream_t stream)
{
    const float* deltas = (const float*)d_in[0];
    const float* labels = (const float*)d_in[1];
    const float* priors = (const float*)d_in[2];
    float* out = (float*)d_out;

    char* ws = (char*)d_ws;
    size_t off = 0;
    float4* boxes = (float4*)(ws + off);            off += (size_t)NROWS * 16;
    unsigned char* bg = (unsigned char*)(ws + off); off += ((size_t)NROWS + 15) & ~15ull;
    int* cnt_g = (int*)(ws + off);                  off += ((size_t)BB * CC * 4 + 15) & ~15ull;
    u64* cand_g = (u64*)(ws + off);                 off += (size_t)BB * CC * CAND_CAP * 8;
    float* nms_s = (float*)(ws + off);              off += (size_t)BB * CC * KK * 4;
    int* nms_i = (int*)(ws + off);                  off += (size_t)BB * CC * KK * 4;

    hipMemsetAsync(cnt_g, 0, (size_t)BB * CC * 4, stream);
    k_decode_filter<<<NROWS / 64, 128, 0, stream>>>(deltas, labels, priors,
                                                    boxes, bg, cnt_g, cand_g);
    k_nms<<<BB * CC, 256, 0, stream>>>(labels, bg, boxes, cnt_g, cand_g, nms_s, nms_i);
    k_topk<<<BB, 1024, 0, stream>>>(nms_s, nms_i, boxes, out);
}

// Round 4
// 302.328 us; speedup vs baseline: 10.8300x; 2.8314x over previous
//
#include <hip/hip_runtime.h>
#include <math.h>

#define BB 16
#define NN 24564
#define CC 81
#define KK 50
#define MT 200
#define NROWS (BB * NN)
#define RB 384                 // row-blocks per batch: ceil(24564/64)
#define CAND_CAP 1024          // per-(b,c) list capacity (mean ~485, sd ~22 -> 24 sigma)
#define T1 0.98f               // tier-1 score threshold
#define TIER_W 0.02f
#define PADI 32                // ints per counter slot (128B padding)

typedef unsigned long long u64;
typedef unsigned int u32;

__device__ __forceinline__ u64 pack_cand(float s, int n) {
    return ((u64)__float_as_uint(s) << 32) | (u32)(~(u32)n);
}

// descending bitonic sort of P u64 keys in LDS, NT threads
template <int P, int NT>
__device__ __forceinline__ void bitonic_desc(u64* a, int tid) {
    for (int k = 2; k <= P; k <<= 1) {
        for (int j = k >> 1; j > 0; j >>= 1) {
            for (int i = tid; i < P; i += NT) {
                int l = i ^ j;
                if (l > i) {
                    u64 x = a[i], y = a[l];
                    bool sw = (i & k) ? (x > y) : (x < y);
                    if (sw) { a[i] = y; a[l] = x; }
                }
            }
            __syncthreads();
        }
    }
}

// ---------------------------------------------------------------------------
// Kernel 1: fused decode + bg + candidate filter.
// Grid = BB * RB blocks of 64 threads (1 wave). A block owns 64 rows WITHIN
// one batch (tail block: 52 rows, guarded) -- so every ballot group shares b,
// making leader-aggregated atomics exact. Counters are 128B-padded.
// ---------------------------------------------------------------------------
__global__ __launch_bounds__(64) void k_decode_filter(
    const float* __restrict__ deltas, const float* __restrict__ labels,
    const float* __restrict__ priors, float4* __restrict__ boxes,
    unsigned char* __restrict__ bg, int* __restrict__ cnt_g,
    u64* __restrict__ cand_g)
{
    __shared__ float4 lab4[1296];             // 64 rows x 81 floats
    int lane = threadIdx.x;
    int b = blockIdx.x / RB, blk = blockIdx.x - b * RB;
    int row0 = blk * 64;
    int rows = NN - row0; if (rows > 64) rows = 64;   // 64 or 52
    const float4* src = (const float4*)(labels + ((size_t)b * NN + row0) * CC);
    int nf4 = rows * CC / 4;                  // 1296 or 1053 (both integral)
    for (int idx = lane; idx < nf4; idx += 64) lab4[idx] = src[idx];
    __syncthreads();

    const float* L = (const float*)lab4 + lane * CC;  // stale for tail lanes; unused there
    float m = L[0];
    #pragma unroll
    for (int c = 1; c < CC; ++c) m = fmaxf(m, L[c]);
    bool inb = (lane < rows);
    bool isbg = (L[0] >= m);                  // argmax==0 under first-index tie rule
    int n = row0 + lane;
    if (inb) bg[(size_t)b * NN + n] = isbg ? 1 : 0;

    // per-class ballot-aggregated scatter: one returned atomic per (block,class)
    for (int c = 0; c < CC; ++c) {
        float v = L[c];
        bool cand = inb && !isbg && (v > T1);
        u64 mm = __ballot(cand);
        if (mm == 0ull) continue;
        int ldr = __ffsll(mm) - 1;
        int cnt = __popcll(mm);
        int base = 0;
        if (lane == ldr) base = atomicAdd(&cnt_g[(b * CC + c) * PADI], cnt);
        base = __shfl(base, ldr);
        if (cand) {
            int p = base + __popcll(mm & ((1ull << lane) - 1ull));
            if (p < CAND_CAP)
                cand_g[(size_t)(b * CC + c) * CAND_CAP + p] = pack_cand(v, n);
        }
    }

    // box decode (exact numpy op order, FMA-free)
    if (inb) {
        size_t r = (size_t)b * NN + n;
        float4 pr = ((const float4*)priors)[n];
        float ph  = __fsub_rn(pr.z, pr.x);
        float pw  = __fsub_rn(pr.w, pr.y);
        float pcy = __fadd_rn(pr.x, __fmul_rn(0.5f, ph));
        float pcx = __fadd_rn(pr.y, __fmul_rn(0.5f, pw));
        float4 dl = ((const float4*)deltas)[r];
        float d0 = __fmul_rn(dl.x, 0.1f);
        float d1 = __fmul_rn(dl.y, 0.1f);
        float d2 = __fmul_rn(dl.z, 0.2f);
        float d3 = __fmul_rn(dl.w, 0.2f);
        float cy = __fadd_rn(__fmul_rn(d0, ph), pcy);
        float cx = __fadd_rn(__fmul_rn(d1, pw), pcx);
        float hh = __fmul_rn(expf(d2), ph);
        float ww = __fmul_rn(expf(d3), pw);
        float h2 = __fmul_rn(hh, 0.5f);
        float w2 = __fmul_rn(ww, 0.5f);
        float y1 = fminf(fmaxf(__fsub_rn(cy, h2), 0.0f), 1.0f);
        float x1 = fminf(fmaxf(__fsub_rn(cx, w2), 0.0f), 1.0f);
        float y2 = fminf(fmaxf(__fadd_rn(cy, h2), 0.0f), 1.0f);
        float x2 = fminf(fmaxf(__fadd_rn(cx, w2), 0.0f), 1.0f);
        boxes[r] = make_float4(y1, x1, y2, x2);
    }
}

// ---------------------------------------------------------------------------
// Kernel 2: per-(b,c) sorted-scan greedy NMS. 256 threads.
// Sort <=1024 keys, stage candidate boxes into LDS (one cooperative gather),
// wave-0 serial greedy scan reads LDS only. Exact fallback bands (with
// self-shrinking width) cover overflow -- statistically never run.
// ---------------------------------------------------------------------------
__global__ __launch_bounds__(256) void k_nms(
    const float* __restrict__ labels, const unsigned char* __restrict__ bg,
    const float4* __restrict__ boxes, const int* __restrict__ cnt_g,
    const u64* __restrict__ cand_g,
    float* __restrict__ out_s, int* __restrict__ out_i)
{
    __shared__ u64 arr[CAND_CAP];
    __shared__ float4 sbox[CAND_CAP];
    __shared__ float ks[KK];
    __shared__ int   ki[KK];
    __shared__ int s_kept, s_cnt;

    int bc = blockIdx.x, tid = threadIdx.x;
    int b = bc / CC, c = bc - b * CC;
    const float4* bxb = boxes + (size_t)b * NN;

    int gcnt = cnt_g[bc * PADI];
    bool ovf = gcnt > CAND_CAP;
    int cnt0 = ovf ? 0 : gcnt;
    for (int i = tid; i < CAND_CAP; i += 256)
        arr[i] = (i < cnt0) ? cand_g[(size_t)bc * CAND_CAP + i] : 0ull;
    if (tid == 0) { s_kept = 0; s_cnt = cnt0; }
    __syncthreads();

    float4 kb = make_float4(0.f, 0.f, 0.f, 0.f);
    float  ka = 0.0f;
    float hi = ovf ? 1.0001f : T1;
    float bw = TIER_W;
    bool first = !ovf;

    while (true) {
        if (!first) {
            if (s_kept >= KK || hi <= 0.5f) break;
            float lo = fmaxf(hi - bw, 0.5f);
            if (tid == 0) s_cnt = 0;
            __syncthreads();
            const float* lab = labels + (size_t)b * NN * CC + c;
            const unsigned char* bgb = bg + (size_t)b * NN;
            for (int n = tid; n < NN; n += 256) {
                float v = lab[(size_t)n * CC];
                if (v > lo && v <= hi && v > 0.5f && !bgb[n]) {
                    int p = atomicAdd(&s_cnt, 1);
                    if (p < CAND_CAP) arr[p] = pack_cand(v, n);
                }
            }
            __syncthreads();
            if (s_cnt > CAND_CAP && bw > 1e-7f) {  // band overflow: shrink, retry
                bw *= 0.5f;
                __syncthreads();
                continue;
            }
            int c2 = min(s_cnt, CAND_CAP);
            for (int i = tid; i < CAND_CAP; i += 256)
                if (i >= c2) arr[i] = 0ull;
            hi = lo;
            bw = TIER_W;
            __syncthreads();
        }
        first = false;

        bitonic_desc<CAND_CAP, 256>(arr, tid);   // ends with __syncthreads
        int cnt = min(s_cnt, CAND_CAP);
        for (int i = tid; i < cnt; i += 256) {   // stage boxes, one gather
            int n = (int)(~(u32)arr[i]);
            if ((u32)n < (u32)NN) sbox[i] = bxb[n];   // guard: never faults
        }
        __syncthreads();

        if (tid < 64) {                          // wave 0: serial greedy scan
            int kept = s_kept;
            for (int i = 0; i < cnt; ++i) {
                u64 key = arr[i];
                float sc = __uint_as_float((u32)(key >> 32));
                int n = (int)(~(u32)key);
                float4 cb = sbox[i];
                float a1 = __fmul_rn(__fsub_rn(cb.z, cb.x), __fsub_rn(cb.w, cb.y));
                bool sup = false;
                if (tid < kept) {
                    float iy1 = fmaxf(kb.x, cb.x);
                    float ix1 = fmaxf(kb.y, cb.y);
                    float iy2 = fminf(kb.z, cb.z);
                    float ix2 = fminf(kb.w, cb.w);
                    float ih = fmaxf(__fsub_rn(iy2, iy1), 0.0f);
                    float iw = fmaxf(__fsub_rn(ix2, ix1), 0.0f);
                    float inter = __fmul_rn(ih, iw);
                    float den = __fadd_rn(__fsub_rn(__fadd_rn(ka, a1), inter), 1e-8f);
                    sup = __fdiv_rn(inter, den) > 0.5f;
                }
                if (__ballot(sup) == 0ull) {
                    if (tid == kept) { kb = cb; ka = a1; }
                    if (tid == 0)    { ks[kept] = sc; ki[kept] = n; }
                    ++kept;
                    if (kept == KK) break;
                }
            }
            if (tid == 0) s_kept = kept;
        }
        __syncthreads();
    }

    int kept = min(s_kept, KK);
    for (int k = tid; k < KK; k += 256) {
        out_s[(size_t)bc * KK + k] = (k < kept) ? ks[k] : 0.0f;
        out_i[(size_t)bc * KK + k] = (k < kept) ? ki[k] : 0;
    }
}

// ---------------------------------------------------------------------------
// Kernel 3: per-batch bitonic top-200 (stable) + output assembly.
// ---------------------------------------------------------------------------
__global__ __launch_bounds__(1024) void k_topk(
    const float* __restrict__ nms_s, const int* __restrict__ nms_i,
    const float4* __restrict__ boxes, float* __restrict__ out)
{
    __shared__ u64 arr[4096];
    __shared__ int s_vc;
    int b = blockIdx.x, tid = threadIdx.x;
    for (int i = tid; i < 4096; i += 1024) {
        u64 v = 0ull;
        if (i < CC * KK) {
            float s = nms_s[(size_t)b * CC * KK + i];
            v = ((u64)__float_as_uint(s) << 32) | (u32)(~(u32)i);
        }
        arr[i] = v;
    }
    if (tid == 0) s_vc = 0;
    __syncthreads();

    bitonic_desc<4096, 1024>(arr, tid);

    if (tid < MT) {
        u64 key = arr[tid];
        float sc = __uint_as_float((u32)(key >> 32));
        int fp = (int)(~(u32)key);
        bool valid = sc > 0.0f;
        float4 bb = make_float4(0.f, 0.f, 0.f, 0.f);
        float cls = 0.0f;
        if (valid) {
            int aidx = nms_i[(size_t)b * CC * KK + fp];
            bb = boxes[(size_t)b * NN + aidx];
            cls = (float)(fp / KK);
        }
        ((float4*)out)[(size_t)b * MT + tid] = bb;
        out[(size_t)BB * MT * 4 + (size_t)b * MT + tid] = sc;
        out[(size_t)BB * MT * 5 + (size_t)b * MT + tid] = cls;
        if (valid) atomicAdd(&s_vc, 1);
    }
    __syncthreads();
    if (tid == 0) out[(size_t)BB * MT * 6 + b] = (float)s_vc;
}

// ---------------------------------------------------------------------------
extern "C" void kernel_launch(void* const* d_in, const int* in_sizes, int n_in,
                              void* d_out, int out_size, void* d_ws, size_t ws_size,
                              hipStream_t stream)
{
    const float* deltas = (const float*)d_in[0];
    const float* labels = (const float*)d_in[1];
    const float* priors = (const float*)d_in[2];
    float* out = (float*)d_out;

    char* ws = (char*)d_ws;
    size_t off = 0;
    float4* boxes = (float4*)(ws + off);            off += (size_t)NROWS * 16;
    unsigned char* bg = (unsigned char*)(ws + off); off += ((size_t)NROWS + 127) & ~127ull;
    int* cnt_g = (int*)(ws + off);                  off += (size_t)BB * CC * PADI * 4;
    u64* cand_g = (u64*)(ws + off);                 off += (size_t)BB * CC * CAND_CAP * 8;
    float* nms_s = (float*)(ws + off);              off += (size_t)BB * CC * KK * 4;
    int* nms_i = (int*)(ws + off);                  off += (size_t)BB * CC * KK * 4;

    hipMemsetAsync(cnt_g, 0, (size_t)BB * CC * PADI * 4, stream);
    k_decode_filter<<<BB * RB, 64, 0, stream>>>(deltas, labels, priors,
                                                boxes, bg, cnt_g, cand_g);
    k_nms<<<BB * CC, 256, 0, stream>>>(labels, bg, boxes, cnt_g, cand_g, nms_s, nms_i);
    k_topk<<<BB, 1024, 0, stream>>>(nms_s, nms_i, boxes, out);
}

// Round 5
// 272.964 us; speedup vs baseline: 11.9950x; 1.1076x over previous
//
#include <hip/hip_runtime.h>
#include <math.h>

#define BB 16
#define NN 24564
#define CC 81
#define KK 50
#define MT 200
#define NROWS (BB * NN)
#define RB 384                 // row-blocks per batch: ceil(24564/64)
#define CAND_CAP 1024          // per-(b,c) list capacity (mean ~485, sd ~22 -> 24 sigma)
#define T1 0.98f               // tier-1 score threshold
#define TIER_W 0.02f
#define PADI 32                // ints per counter slot (128B padding)

typedef unsigned long long u64;
typedef unsigned int u32;

__device__ __forceinline__ u64 pack_cand(float s, int n) {
    return ((u64)__float_as_uint(s) << 32) | (u32)(~(u32)n);
}

// descending bitonic sort of P u64 keys in LDS, NT threads
template <int P, int NT>
__device__ __forceinline__ void bitonic_desc(u64* a, int tid) {
    for (int k = 2; k <= P; k <<= 1) {
        for (int j = k >> 1; j > 0; j >>= 1) {
            for (int i = tid; i < P; i += NT) {
                int l = i ^ j;
                if (l > i) {
                    u64 x = a[i], y = a[l];
                    bool sw = (i & k) ? (x > y) : (x < y);
                    if (sw) { a[i] = y; a[l] = x; }
                }
            }
            __syncthreads();
        }
    }
}

// ---------------------------------------------------------------------------
// Kernel 1: fused decode + bg + candidate filter. 1 wave per block, 64 rows
// within one batch. Atomic allocation is done ONCE per class by 81 parallel
// lanes (2 instructions total) instead of ~57 serialized leader round-trips.
// ---------------------------------------------------------------------------
__global__ __launch_bounds__(64) void k_decode_filter(
    const float* __restrict__ deltas, const float* __restrict__ labels,
    const float* __restrict__ priors, float4* __restrict__ boxes,
    unsigned char* __restrict__ bg, int* __restrict__ cnt_g,
    u64* __restrict__ cand_g)
{
    __shared__ float4 lab4[1296];             // 64 rows x 81 floats
    __shared__ u64 s_mask[CC];
    __shared__ int s_base[CC];

    int lane = threadIdx.x;
    int b = blockIdx.x / RB, blk = blockIdx.x - b * RB;
    int row0 = blk * 64;
    int rows = NN - row0; if (rows > 64) rows = 64;   // 64 or 52
    const float4* src = (const float4*)(labels + ((size_t)b * NN + row0) * CC);
    int nf4 = rows * CC / 4;                  // 1296 or 1053 (both integral)

    // staged load: fixed 21-deep unrolled predicated float4 copy (full MLP)
    float4 tmp[21];
    #pragma unroll
    for (int j = 0; j < 21; ++j) {
        int idx = j * 64 + lane;
        if (idx < nf4) tmp[j] = src[idx];
    }
    #pragma unroll
    for (int j = 0; j < 21; ++j) {
        int idx = j * 64 + lane;
        if (idx < nf4) lab4[idx] = tmp[j];
    }
    __syncthreads();

    // single pass: rowmax + per-lane 81-bit candidate premask
    const float* L = (const float*)lab4 + lane * CC;
    bool inb = (lane < rows);
    float L0 = L[0];
    float m = L0;
    u32 pre0 = 0, pre1 = 0, pre2 = 0;
    #pragma unroll
    for (int c = 0; c < CC; ++c) {
        float v = L[c];
        m = fmaxf(m, v);
        if (v > T1) {
            if (c < 32)      pre0 |= 1u << c;
            else if (c < 64) pre1 |= 1u << (c - 32);
            else             pre2 |= 1u << (c - 64);
        }
    }
    bool isbg = (L0 >= m);                    // argmax==0, first-index tie rule
    int n = row0 + lane;
    if (inb) bg[(size_t)b * NN + n] = isbg ? 1 : 0;
    bool act = inb && !isbg;

    // phase 1: per-class ballot masks into LDS (no memory latency)
    #pragma unroll
    for (int c = 0; c < CC; ++c) {
        u32 w = (c < 32) ? pre0 : ((c < 64) ? pre1 : pre2);
        bool cand = act && ((w >> (c & 31)) & 1u);
        u64 mm = __ballot(cand);
        if (lane == 0) s_mask[c] = mm;
    }
    __syncthreads();

    // phase 2: 81 concurrent slot allocations (2 atomic instructions total)
    {
        u64 m2 = s_mask[lane];
        int base2 = 0;
        if (m2) base2 = atomicAdd(&cnt_g[(b * CC + lane) * PADI], (int)__popcll(m2));
        s_base[lane] = base2;
        int c3 = 64 + lane;
        if (c3 < CC) {
            u64 m3 = s_mask[c3];
            int base3 = 0;
            if (m3) base3 = atomicAdd(&cnt_g[(b * CC + c3) * PADI], (int)__popcll(m3));
            s_base[c3] = base3;
        }
    }
    __syncthreads();

    // phase 3: ranked fire-and-forget scatter
    u64 ltmask = (lane == 63) ? ~0ull >> 1 : ((1ull << lane) - 1ull);
    if (lane == 63) ltmask = 0x7FFFFFFFFFFFFFFFull;
    for (int c = 0; c < CC; ++c) {
        u64 mm = s_mask[c];
        if (mm == 0ull) continue;
        u32 w = (c < 32) ? pre0 : ((c < 64) ? pre1 : pre2);
        bool bit = act && ((w >> (c & 31)) & 1u);
        if (bit) {
            int p = s_base[c] + (int)__popcll(mm & ltmask);
            if (p < CAND_CAP)
                cand_g[(size_t)(b * CC + c) * CAND_CAP + p] = pack_cand(L[c], n);
        }
    }

    // box decode (exact numpy op order, FMA-free)
    if (inb) {
        size_t r = (size_t)b * NN + n;
        float4 pr = ((const float4*)priors)[n];
        float ph  = __fsub_rn(pr.z, pr.x);
        float pw  = __fsub_rn(pr.w, pr.y);
        float pcy = __fadd_rn(pr.x, __fmul_rn(0.5f, ph));
        float pcx = __fadd_rn(pr.y, __fmul_rn(0.5f, pw));
        float4 dl = ((const float4*)deltas)[r];
        float d0 = __fmul_rn(dl.x, 0.1f);
        float d1 = __fmul_rn(dl.y, 0.1f);
        float d2 = __fmul_rn(dl.z, 0.2f);
        float d3 = __fmul_rn(dl.w, 0.2f);
        float cy = __fadd_rn(__fmul_rn(d0, ph), pcy);
        float cx = __fadd_rn(__fmul_rn(d1, pw), pcx);
        float hh = __fmul_rn(expf(d2), ph);
        float ww = __fmul_rn(expf(d3), pw);
        float h2 = __fmul_rn(hh, 0.5f);
        float w2 = __fmul_rn(ww, 0.5f);
        float y1 = fminf(fmaxf(__fsub_rn(cy, h2), 0.0f), 1.0f);
        float x1 = fminf(fmaxf(__fsub_rn(cx, w2), 0.0f), 1.0f);
        float y2 = fminf(fmaxf(__fadd_rn(cy, h2), 0.0f), 1.0f);
        float x2 = fminf(fmaxf(__fadd_rn(cx, w2), 0.0f), 1.0f);
        boxes[r] = make_float4(y1, x1, y2, x2);
    }
}

// ---------------------------------------------------------------------------
// Kernel 2: per-(b,c) sorted-scan greedy NMS. 256 threads. (unchanged, exact)
// ---------------------------------------------------------------------------
__global__ __launch_bounds__(256) void k_nms(
    const float* __restrict__ labels, const unsigned char* __restrict__ bg,
    const float4* __restrict__ boxes, const int* __restrict__ cnt_g,
    const u64* __restrict__ cand_g,
    float* __restrict__ out_s, int* __restrict__ out_i)
{
    __shared__ u64 arr[CAND_CAP];
    __shared__ float4 sbox[CAND_CAP];
    __shared__ float ks[KK];
    __shared__ int   ki[KK];
    __shared__ int s_kept, s_cnt;

    int bc = blockIdx.x, tid = threadIdx.x;
    int b = bc / CC, c = bc - b * CC;
    const float4* bxb = boxes + (size_t)b * NN;

    int gcnt = cnt_g[bc * PADI];
    bool ovf = gcnt > CAND_CAP;
    int cnt0 = ovf ? 0 : gcnt;
    for (int i = tid; i < CAND_CAP; i += 256)
        arr[i] = (i < cnt0) ? cand_g[(size_t)bc * CAND_CAP + i] : 0ull;
    if (tid == 0) { s_kept = 0; s_cnt = cnt0; }
    __syncthreads();

    float4 kb = make_float4(0.f, 0.f, 0.f, 0.f);
    float  ka = 0.0f;
    float hi = ovf ? 1.0001f : T1;
    float bw = TIER_W;
    bool first = !ovf;

    while (true) {
        if (!first) {
            if (s_kept >= KK || hi <= 0.5f) break;
            float lo = fmaxf(hi - bw, 0.5f);
            if (tid == 0) s_cnt = 0;
            __syncthreads();
            const float* lab = labels + (size_t)b * NN * CC + c;
            const unsigned char* bgb = bg + (size_t)b * NN;
            for (int n = tid; n < NN; n += 256) {
                float v = lab[(size_t)n * CC];
                if (v > lo && v <= hi && v > 0.5f && !bgb[n]) {
                    int p = atomicAdd(&s_cnt, 1);
                    if (p < CAND_CAP) arr[p] = pack_cand(v, n);
                }
            }
            __syncthreads();
            if (s_cnt > CAND_CAP && bw > 1e-7f) {  // band overflow: shrink, retry
                bw *= 0.5f;
                __syncthreads();
                continue;
            }
            int c2 = min(s_cnt, CAND_CAP);
            for (int i = tid; i < CAND_CAP; i += 256)
                if (i >= c2) arr[i] = 0ull;
            hi = lo;
            bw = TIER_W;
            __syncthreads();
        }
        first = false;

        bitonic_desc<CAND_CAP, 256>(arr, tid);   // ends with __syncthreads
        int cnt = min(s_cnt, CAND_CAP);
        for (int i = tid; i < cnt; i += 256) {   // stage boxes, one gather
            int n = (int)(~(u32)arr[i]);
            if ((u32)n < (u32)NN) sbox[i] = bxb[n];   // guard: never faults
        }
        __syncthreads();

        if (tid < 64) {                          // wave 0: serial greedy scan
            int kept = s_kept;
            for (int i = 0; i < cnt; ++i) {
                u64 key = arr[i];
                float sc = __uint_as_float((u32)(key >> 32));
                int n = (int)(~(u32)key);
                float4 cb = sbox[i];
                float a1 = __fmul_rn(__fsub_rn(cb.z, cb.x), __fsub_rn(cb.w, cb.y));
                bool sup = false;
                if (tid < kept) {
                    float iy1 = fmaxf(kb.x, cb.x);
                    float ix1 = fmaxf(kb.y, cb.y);
                    float iy2 = fminf(kb.z, cb.z);
                    float ix2 = fminf(kb.w, cb.w);
                    float ih = fmaxf(__fsub_rn(iy2, iy1), 0.0f);
                    float iw = fmaxf(__fsub_rn(ix2, ix1), 0.0f);
                    float inter = __fmul_rn(ih, iw);
                    float den = __fadd_rn(__fsub_rn(__fadd_rn(ka, a1), inter), 1e-8f);
                    sup = __fdiv_rn(inter, den) > 0.5f;
                }
                if (__ballot(sup) == 0ull) {
                    if (tid == kept) { kb = cb; ka = a1; }
                    if (tid == 0)    { ks[kept] = sc; ki[kept] = n; }
                    ++kept;
                    if (kept == KK) break;
                }
            }
            if (tid == 0) s_kept = kept;
        }
        __syncthreads();
    }

    int kept = min(s_kept, KK);
    for (int k = tid; k < KK; k += 256) {
        out_s[(size_t)bc * KK + k] = (k < kept) ? ks[k] : 0.0f;
        out_i[(size_t)bc * KK + k] = (k < kept) ? ki[k] : 0;
    }
}

// ---------------------------------------------------------------------------
// Kernel 3: per-batch bitonic top-200 (stable) + output assembly. (unchanged)
// ---------------------------------------------------------------------------
__global__ __launch_bounds__(1024) void k_topk(
    const float* __restrict__ nms_s, const int* __restrict__ nms_i,
    const float4* __restrict__ boxes, float* __restrict__ out)
{
    __shared__ u64 arr[4096];
    __shared__ int s_vc;
    int b = blockIdx.x, tid = threadIdx.x;
    for (int i = tid; i < 4096; i += 1024) {
        u64 v = 0ull;
        if (i < CC * KK) {
            float s = nms_s[(size_t)b * CC * KK + i];
            v = ((u64)__float_as_uint(s) << 32) | (u32)(~(u32)i);
        }
        arr[i] = v;
    }
    if (tid == 0) s_vc = 0;
    __syncthreads();

    bitonic_desc<4096, 1024>(arr, tid);

    if (tid < MT) {
        u64 key = arr[tid];
        float sc = __uint_as_float((u32)(key >> 32));
        int fp = (int)(~(u32)key);
        bool valid = sc > 0.0f;
        float4 bb = make_float4(0.f, 0.f, 0.f, 0.f);
        float cls = 0.0f;
        if (valid) {
            int aidx = nms_i[(size_t)b * CC * KK + fp];
            bb = boxes[(size_t)b * NN + aidx];
            cls = (float)(fp / KK);
        }
        ((float4*)out)[(size_t)b * MT + tid] = bb;
        out[(size_t)BB * MT * 4 + (size_t)b * MT + tid] = sc;
        out[(size_t)BB * MT * 5 + (size_t)b * MT + tid] = cls;
        if (valid) atomicAdd(&s_vc, 1);
    }
    __syncthreads();
    if (tid == 0) out[(size_t)BB * MT * 6 + b] = (float)s_vc;
}

// ---------------------------------------------------------------------------
extern "C" void kernel_launch(void* const* d_in, const int* in_sizes, int n_in,
                              void* d_out, int out_size, void* d_ws, size_t ws_size,
                              hipStream_t stream)
{
    const float* deltas = (const float*)d_in[0];
    const float* labels = (const float*)d_in[1];
    const float* priors = (const float*)d_in[2];
    float* out = (float*)d_out;

    char* ws = (char*)d_ws;
    size_t off = 0;
    float4* boxes = (float4*)(ws + off);            off += (size_t)NROWS * 16;
    unsigned char* bg = (unsigned char*)(ws + off); off += ((size_t)NROWS + 127) & ~127ull;
    int* cnt_g = (int*)(ws + off);                  off += (size_t)BB * CC * PADI * 4;
    u64* cand_g = (u64*)(ws + off);                 off += (size_t)BB * CC * CAND_CAP * 8;
    float* nms_s = (float*)(ws + off);              off += (size_t)BB * CC * KK * 4;
    int* nms_i = (int*)(ws + off);                  off += (size_t)BB * CC * KK * 4;

    hipMemsetAsync(cnt_g, 0, (size_t)BB * CC * PADI * 4, stream);
    k_decode_filter<<<BB * RB, 64, 0, stream>>>(deltas, labels, priors,
                                                boxes, bg, cnt_g, cand_g);
    k_nms<<<BB * CC, 256, 0, stream>>>(labels, bg, boxes, cnt_g, cand_g, nms_s, nms_i);
    k_topk<<<BB, 1024, 0, stream>>>(nms_s, nms_i, boxes, out);
}

// Round 6
// 213.935 us; speedup vs baseline: 15.3047x; 1.2759x over previous
//
#include <hip/hip_runtime.h>
#include <math.h>

#define BB 16
#define NN 24564
#define CC 81
#define KK 50
#define MT 200
#define NROWS (BB * NN)
#define RB 384                 // row-blocks per batch: ceil(24564/64)
#define CAND_CAP 1024          // per-(b,c) list capacity (mean ~485, sd ~22 -> 24 sigma)
#define T1 0.98f               // tier-1 score threshold
#define TIER_W 0.02f
#define PADI 32                // ints per counter slot (128B padding)

typedef unsigned long long u64;
typedef unsigned int u32;

__device__ __forceinline__ u64 pack_cand(float s, int n) {
    return ((u64)__float_as_uint(s) << 32) | (u32)(~(u32)n);
}

// descending bitonic sort of P u64 keys in LDS, NT threads
template <int P, int NT>
__device__ __forceinline__ void bitonic_desc(u64* a, int tid) {
    for (int k = 2; k <= P; k <<= 1) {
        for (int j = k >> 1; j > 0; j >>= 1) {
            for (int i = tid; i < P; i += NT) {
                int l = i ^ j;
                if (l > i) {
                    u64 x = a[i], y = a[l];
                    bool sw = (i & k) ? (x > y) : (x < y);
                    if (sw) { a[i] = y; a[l] = x; }
                }
            }
            __syncthreads();
        }
    }
}

// ---------------------------------------------------------------------------
// Kernel 1: fused decode + bg + candidate filter. 1 wave per block, 64 rows
// within one batch. Labels staged via async global_load_lds (no VGPR
// round-trip, no spill, ~20 loads in flight). Atomic allocation: 81 parallel
// lane-atomics (2 instructions) per block.
// ---------------------------------------------------------------------------
__global__ __launch_bounds__(64) void k_decode_filter(
    const float* __restrict__ deltas, const float* __restrict__ labels,
    const float* __restrict__ priors, float4* __restrict__ boxes,
    unsigned char* __restrict__ bg, int* __restrict__ cnt_g,
    u64* __restrict__ cand_g)
{
    __shared__ float4 lab4[1296];             // 64 rows x 81 floats
    __shared__ u64 s_mask[CC];
    __shared__ int s_base[CC];

    int lane = threadIdx.x;
    int b = blockIdx.x / RB, blk = blockIdx.x - b * RB;
    int row0 = blk * 64;
    int rows = NN - row0; if (rows > 64) rows = 64;   // 64 or 52
    const float4* src = (const float4*)(labels + ((size_t)b * NN + row0) * CC);
    int nf4 = rows * CC / 4;                  // 1296 or 1053 (both integral)

    // async staged load: full 64-float4 chunks direct global->LDS
    int nfull = nf4 >> 6;                     // 20 (full) or 16 (tail block)
    for (int j = 0; j < nfull; ++j) {
        __builtin_amdgcn_global_load_lds(
            (const __attribute__((address_space(1))) void*)(src + (j << 6) + lane),
            (__attribute__((address_space(3))) void*)(lab4 + (j << 6)),
            16, 0, 0);
    }
    // remainder (16 or 29 float4): plain predicated copy
    int idx = (nfull << 6) + lane;
    bool hasrem = idx < nf4;
    float4 tv;
    if (hasrem) tv = src[idx];
    asm volatile("s_waitcnt vmcnt(0)" ::: "memory");
    if (hasrem) lab4[idx] = tv;
    __syncthreads();

    // single pass: rowmax + per-lane 81-bit candidate premask
    const float* L = (const float*)lab4 + lane * CC;
    bool inb = (lane < rows);
    float L0 = L[0];
    float m = L0;
    u32 pre0 = 0, pre1 = 0, pre2 = 0;
    #pragma unroll
    for (int c = 0; c < CC; ++c) {
        float v = L[c];
        m = fmaxf(m, v);
        if (v > T1) {
            if (c < 32)      pre0 |= 1u << c;
            else if (c < 64) pre1 |= 1u << (c - 32);
            else             pre2 |= 1u << (c - 64);
        }
    }
    bool isbg = (L0 >= m);                    // argmax==0, first-index tie rule
    int n = row0 + lane;
    if (inb) bg[(size_t)b * NN + n] = isbg ? 1 : 0;
    bool act = inb && !isbg;

    // phase 1: per-class ballot masks into LDS (no memory latency)
    #pragma unroll
    for (int c = 0; c < CC; ++c) {
        u32 w = (c < 32) ? pre0 : ((c < 64) ? pre1 : pre2);
        bool cand = act && ((w >> (c & 31)) & 1u);
        u64 mm = __ballot(cand);
        if (lane == 0) s_mask[c] = mm;
    }
    __syncthreads();

    // phase 2: 81 concurrent slot allocations (2 atomic instructions total)
    {
        u64 m2 = s_mask[lane];
        int base2 = 0;
        if (m2) base2 = atomicAdd(&cnt_g[(b * CC + lane) * PADI], (int)__popcll(m2));
        s_base[lane] = base2;
        int c3 = 64 + lane;
        if (c3 < CC) {
            u64 m3 = s_mask[c3];
            int base3 = 0;
            if (m3) base3 = atomicAdd(&cnt_g[(b * CC + c3) * PADI], (int)__popcll(m3));
            s_base[c3] = base3;
        }
    }
    __syncthreads();

    // phase 3: ranked fire-and-forget scatter
    u64 ltmask = (lane == 63) ? 0x7FFFFFFFFFFFFFFFull : ((1ull << lane) - 1ull);
    for (int c = 0; c < CC; ++c) {
        u64 mm = s_mask[c];
        if (mm == 0ull) continue;
        u32 w = (c < 32) ? pre0 : ((c < 64) ? pre1 : pre2);
        bool bit = act && ((w >> (c & 31)) & 1u);
        if (bit) {
            int p = s_base[c] + (int)__popcll(mm & ltmask);
            if (p < CAND_CAP)
                cand_g[(size_t)(b * CC + c) * CAND_CAP + p] = pack_cand(L[c], n);
        }
    }

    // box decode (exact numpy op order, FMA-free)
    if (inb) {
        size_t r = (size_t)b * NN + n;
        float4 pr = ((const float4*)priors)[n];
        float ph  = __fsub_rn(pr.z, pr.x);
        float pw  = __fsub_rn(pr.w, pr.y);
        float pcy = __fadd_rn(pr.x, __fmul_rn(0.5f, ph));
        float pcx = __fadd_rn(pr.y, __fmul_rn(0.5f, pw));
        float4 dl = ((const float4*)deltas)[r];
        float d0 = __fmul_rn(dl.x, 0.1f);
        float d1 = __fmul_rn(dl.y, 0.1f);
        float d2 = __fmul_rn(dl.z, 0.2f);
        float d3 = __fmul_rn(dl.w, 0.2f);
        float cy = __fadd_rn(__fmul_rn(d0, ph), pcy);
        float cx = __fadd_rn(__fmul_rn(d1, pw), pcx);
        float hh = __fmul_rn(expf(d2), ph);
        float ww = __fmul_rn(expf(d3), pw);
        float h2 = __fmul_rn(hh, 0.5f);
        float w2 = __fmul_rn(ww, 0.5f);
        float y1 = fminf(fmaxf(__fsub_rn(cy, h2), 0.0f), 1.0f);
        float x1 = fminf(fmaxf(__fsub_rn(cx, w2), 0.0f), 1.0f);
        float y2 = fminf(fmaxf(__fadd_rn(cy, h2), 0.0f), 1.0f);
        float x2 = fminf(fmaxf(__fadd_rn(cx, w2), 0.0f), 1.0f);
        boxes[r] = make_float4(y1, x1, y2, x2);
    }
}

// ---------------------------------------------------------------------------
// Kernel 2: per-(b,c) sorted-scan greedy NMS. 256 threads. (unchanged, exact)
// ---------------------------------------------------------------------------
__global__ __launch_bounds__(256) void k_nms(
    const float* __restrict__ labels, const unsigned char* __restrict__ bg,
    const float4* __restrict__ boxes, const int* __restrict__ cnt_g,
    const u64* __restrict__ cand_g,
    float* __restrict__ out_s, int* __restrict__ out_i)
{
    __shared__ u64 arr[CAND_CAP];
    __shared__ float4 sbox[CAND_CAP];
    __shared__ float ks[KK];
    __shared__ int   ki[KK];
    __shared__ int s_kept, s_cnt;

    int bc = blockIdx.x, tid = threadIdx.x;
    int b = bc / CC, c = bc - b * CC;
    const float4* bxb = boxes + (size_t)b * NN;

    int gcnt = cnt_g[bc * PADI];
    bool ovf = gcnt > CAND_CAP;
    int cnt0 = ovf ? 0 : gcnt;
    for (int i = tid; i < CAND_CAP; i += 256)
        arr[i] = (i < cnt0) ? cand_g[(size_t)bc * CAND_CAP + i] : 0ull;
    if (tid == 0) { s_kept = 0; s_cnt = cnt0; }
    __syncthreads();

    float4 kb = make_float4(0.f, 0.f, 0.f, 0.f);
    float  ka = 0.0f;
    float hi = ovf ? 1.0001f : T1;
    float bw = TIER_W;
    bool first = !ovf;

    while (true) {
        if (!first) {
            if (s_kept >= KK || hi <= 0.5f) break;
            float lo = fmaxf(hi - bw, 0.5f);
            if (tid == 0) s_cnt = 0;
            __syncthreads();
            const float* lab = labels + (size_t)b * NN * CC + c;
            const unsigned char* bgb = bg + (size_t)b * NN;
            for (int n = tid; n < NN; n += 256) {
                float v = lab[(size_t)n * CC];
                if (v > lo && v <= hi && v > 0.5f && !bgb[n]) {
                    int p = atomicAdd(&s_cnt, 1);
                    if (p < CAND_CAP) arr[p] = pack_cand(v, n);
                }
            }
            __syncthreads();
            if (s_cnt > CAND_CAP && bw > 1e-7f) {  // band overflow: shrink, retry
                bw *= 0.5f;
                __syncthreads();
                continue;
            }
            int c2 = min(s_cnt, CAND_CAP);
            for (int i = tid; i < CAND_CAP; i += 256)
                if (i >= c2) arr[i] = 0ull;
            hi = lo;
            bw = TIER_W;
            __syncthreads();
        }
        first = false;

        bitonic_desc<CAND_CAP, 256>(arr, tid);   // ends with __syncthreads
        int cnt = min(s_cnt, CAND_CAP);
        for (int i = tid; i < cnt; i += 256) {   // stage boxes, one gather
            int n = (int)(~(u32)arr[i]);
            if ((u32)n < (u32)NN) sbox[i] = bxb[n];   // guard: never faults
        }
        __syncthreads();

        if (tid < 64) {                          // wave 0: serial greedy scan
            int kept = s_kept;
            for (int i = 0; i < cnt; ++i) {
                u64 key = arr[i];
                float sc = __uint_as_float((u32)(key >> 32));
                int n = (int)(~(u32)key);
                float4 cb = sbox[i];
                float a1 = __fmul_rn(__fsub_rn(cb.z, cb.x), __fsub_rn(cb.w, cb.y));
                bool sup = false;
                if (tid < kept) {
                    float iy1 = fmaxf(kb.x, cb.x);
                    float ix1 = fmaxf(kb.y, cb.y);
                    float iy2 = fminf(kb.z, cb.z);
                    float ix2 = fminf(kb.w, cb.w);
                    float ih = fmaxf(__fsub_rn(iy2, iy1), 0.0f);
                    float iw = fmaxf(__fsub_rn(ix2, ix1), 0.0f);
                    float inter = __fmul_rn(ih, iw);
                    float den = __fadd_rn(__fsub_rn(__fadd_rn(ka, a1), inter), 1e-8f);
                    sup = __fdiv_rn(inter, den) > 0.5f;
                }
                if (__ballot(sup) == 0ull) {
                    if (tid == kept) { kb = cb; ka = a1; }
                    if (tid == 0)    { ks[kept] = sc; ki[kept] = n; }
                    ++kept;
                    if (kept == KK) break;
                }
            }
            if (tid == 0) s_kept = kept;
        }
        __syncthreads();
    }

    int kept = min(s_kept, KK);
    for (int k = tid; k < KK; k += 256) {
        out_s[(size_t)bc * KK + k] = (k < kept) ? ks[k] : 0.0f;
        out_i[(size_t)bc * KK + k] = (k < kept) ? ki[k] : 0;
    }
}

// ---------------------------------------------------------------------------
// Kernel 3: per-batch bitonic top-200 (stable) + output assembly. (unchanged)
// ---------------------------------------------------------------------------
__global__ __launch_bounds__(1024) void k_topk(
    const float* __restrict__ nms_s, const int* __restrict__ nms_i,
    const float4* __restrict__ boxes, float* __restrict__ out)
{
    __shared__ u64 arr[4096];
    __shared__ int s_vc;
    int b = blockIdx.x, tid = threadIdx.x;
    for (int i = tid; i < 4096; i += 1024) {
        u64 v = 0ull;
        if (i < CC * KK) {
            float s = nms_s[(size_t)b * CC * KK + i];
            v = ((u64)__float_as_uint(s) << 32) | (u32)(~(u32)i);
        }
        arr[i] = v;
    }
    if (tid == 0) s_vc = 0;
    __syncthreads();

    bitonic_desc<4096, 1024>(arr, tid);

    if (tid < MT) {
        u64 key = arr[tid];
        float sc = __uint_as_float((u32)(key >> 32));
        int fp = (int)(~(u32)key);
        bool valid = sc > 0.0f;
        float4 bb = make_float4(0.f, 0.f, 0.f, 0.f);
        float cls = 0.0f;
        if (valid) {
            int aidx = nms_i[(size_t)b * CC * KK + fp];
            bb = boxes[(size_t)b * NN + aidx];
            cls = (float)(fp / KK);
        }
        ((float4*)out)[(size_t)b * MT + tid] = bb;
        out[(size_t)BB * MT * 4 + (size_t)b * MT + tid] = sc;
        out[(size_t)BB * MT * 5 + (size_t)b * MT + tid] = cls;
        if (valid) atomicAdd(&s_vc, 1);
    }
    __syncthreads();
    if (tid == 0) out[(size_t)BB * MT * 6 + b] = (float)s_vc;
}

// ---------------------------------------------------------------------------
extern "C" void kernel_launch(void* const* d_in, const int* in_sizes, int n_in,
                              void* d_out, int out_size, void* d_ws, size_t ws_size,
                              hipStream_t stream)
{
    const float* deltas = (const float*)d_in[0];
    const float* labels = (const float*)d_in[1];
    const float* priors = (const float*)d_in[2];
    float* out = (float*)d_out;

    char* ws = (char*)d_ws;
    size_t off = 0;
    float4* boxes = (float4*)(ws + off);            off += (size_t)NROWS * 16;
    unsigned char* bg = (unsigned char*)(ws + off); off += ((size_t)NROWS + 127) & ~127ull;
    int* cnt_g = (int*)(ws + off);                  off += (size_t)BB * CC * PADI * 4;
    u64* cand_g = (u64*)(ws + off);                 off += (size_t)BB * CC * CAND_CAP * 8;
    float* nms_s = (float*)(ws + off);              off += (size_t)BB * CC * KK * 4;
    int* nms_i = (int*)(ws + off);                  off += (size_t)BB * CC * KK * 4;

    hipMemsetAsync(cnt_g, 0, (size_t)BB * CC * PADI * 4, stream);
    k_decode_filter<<<BB * RB, 64, 0, stream>>>(deltas, labels, priors,
                                                boxes, bg, cnt_g, cand_g);
    k_nms<<<BB * CC, 256, 0, stream>>>(labels, bg, boxes, cnt_g, cand_g, nms_s, nms_i);
    k_topk<<<BB, 1024, 0, stream>>>(nms_s, nms_i, boxes, out);
}

// Round 7
// 186.463 us; speedup vs baseline: 17.5596x; 1.1473x over previous
//
#include <hip/hip_runtime.h>
#include <math.h>

#define BB 16
#define NN 24564
#define CC 81
#define KK 50
#define MT 200
#define NROWS (BB * NN)
#define RB 384                 // row-blocks per batch: ceil(24564/64)
#define CAND_CAP 1024          // per-(b,c) list capacity (mean ~485, sd ~22 -> 24 sigma)
#define T1 0.98f               // tier-1 score threshold
#define TIER_W 0.02f
#define PADI 32                // ints per counter slot (128B padding)

typedef unsigned long long u64;
typedef unsigned int u32;

__device__ __forceinline__ u64 pack_cand(float s, int n) {
    return ((u64)__float_as_uint(s) << 32) | (u32)(~(u32)n);
}

// descending bitonic sort of P u64 keys in LDS, NT threads
template <int P, int NT>
__device__ __forceinline__ void bitonic_desc(u64* a, int tid) {
    for (int k = 2; k <= P; k <<= 1) {
        for (int j = k >> 1; j > 0; j >>= 1) {
            for (int i = tid; i < P; i += NT) {
                int l = i ^ j;
                if (l > i) {
                    u64 x = a[i], y = a[l];
                    bool sw = (i & k) ? (x > y) : (x < y);
                    if (sw) { a[i] = y; a[l] = x; }
                }
            }
            __syncthreads();
        }
    }
}

// ---------------------------------------------------------------------------
// Kernel 1: fused decode + bg + candidate filter.
// 128 threads = 2 waves per block; block owns 64 rows within one batch.
// Each wave owns 32 rows with 2 lanes/row (h=0: classes 0..40, h=1: 41..80).
// Labels staged via async global_load_lds (per-wave interleaved chunks).
// Per-wave ballot masks + 81 parallel lane-atomics; window-bit scatter.
// ---------------------------------------------------------------------------
__global__ __launch_bounds__(128) void k_decode_filter(
    const float* __restrict__ deltas, const float* __restrict__ labels,
    const float* __restrict__ priors, float4* __restrict__ boxes,
    unsigned char* __restrict__ bg, int* __restrict__ cnt_g,
    u64* __restrict__ cand_g)
{
    __shared__ float4 lab4[1296];             // 64 rows x 81 floats
    __shared__ u64 s_mask[2][CC];
    __shared__ int s_base[2][CC];

    int tid = threadIdx.x;
    int w = tid >> 6, lane = tid & 63;
    int b = blockIdx.x / RB, blk = blockIdx.x - b * RB;
    int row0 = blk * 64;
    int rows = NN - row0; if (rows > 64) rows = 64;   // 64 or 52
    const float4* src = (const float4*)(labels + ((size_t)b * NN + row0) * CC);
    int nf4 = rows * CC / 4;                  // 1296 or 1053 (both integral)

    // async staging: waves interleave over full 64-float4 chunks
    int nfull = nf4 >> 6;                     // 20 (full) or 16 (tail block)
    for (int j = w; j < nfull; j += 2) {
        __builtin_amdgcn_global_load_lds(
            (const __attribute__((address_space(1))) void*)(src + (j << 6) + lane),
            (__attribute__((address_space(3))) void*)(lab4 + (j << 6)),
            16, 0, 0);
    }
    // remainder (16 or 29 float4): predicated copy by 128 threads
    int idx = (nfull << 6) + tid;
    bool hasrem = idx < nf4;
    float4 tv;
    if (hasrem) tv = src[idx];
    asm volatile("s_waitcnt vmcnt(0)" ::: "memory");
    if (hasrem) lab4[idx] = tv;
    __syncthreads();

    int rl = w * 32 + (lane & 31);            // row within block
    int h = lane >> 5;                        // class-half owner
    bool inb = rl < rows;
    int n = row0 + rl;
    const float* L = (const float*)lab4 + rl * CC;

    int c0 = h ? 41 : 0, c1 = h ? 81 : 41;
    float L0 = L[0];
    float m = L[c0];
    u64 win = 0;                              // own-half candidate bits
    for (int c = c0; c < c1; ++c) {
        float v = L[c];
        m = fmaxf(m, v);
        if (v > T1) win |= 1ull << (c - c0);
    }
    float rm = fmaxf(m, __shfl_xor(m, 32));
    bool isbg = (L0 >= rm);                   // argmax==0, first-index tie rule
    if (inb && h == 0) bg[(size_t)b * NN + n] = isbg ? 1 : 0;
    if (!(inb && !isbg)) win = 0;

    // phase 1: per-class ballots into per-wave LDS masks
    for (int c = 0; c < CC; ++c) {
        int ho = (c >= 41);
        int j = c - (ho ? 41 : 0);
        bool cand = (h == ho) && ((win >> j) & 1);
        u64 mm = __ballot(cand);
        if (lane == 0) s_mask[w][c] = mm;
    }
    __syncthreads();

    // phase 2: 81 concurrent slot allocations per wave (2 atomic instrs)
    {
        u64 m2 = s_mask[w][lane];
        int v2 = 0;
        if (m2) v2 = atomicAdd(&cnt_g[(b * CC + lane) * PADI], (int)__popcll(m2));
        s_base[w][lane] = v2;
        int c3 = 64 + lane;
        if (c3 < CC) {
            u64 m3 = s_mask[w][c3];
            int v3 = 0;
            if (m3) v3 = atomicAdd(&cnt_g[(b * CC + c3) * PADI], (int)__popcll(m3));
            s_base[w][c3] = v3;
        }
    }
    __syncthreads();

    // phase 3: ranked fire-and-forget scatter over own window bits
    u64 ltmask = (lane == 63) ? 0x7FFFFFFFFFFFFFFFull : ((1ull << lane) - 1ull);
    u64 wrem = win;
    while (wrem) {
        int j = __ffsll(wrem) - 1;
        wrem &= wrem - 1;
        int c = h * 41 + j;
        u64 mm = s_mask[w][c];
        int p = s_base[w][c] + (int)__popcll(mm & ltmask);
        if (p < CAND_CAP)
            cand_g[(size_t)(b * CC + c) * CAND_CAP + p] = pack_cand(L[c], n);
    }

    // box decode (exact numpy op order, FMA-free); h==0 lane per row
    if (inb && h == 0) {
        size_t r = (size_t)b * NN + n;
        float4 pr = ((const float4*)priors)[n];
        float ph  = __fsub_rn(pr.z, pr.x);
        float pw  = __fsub_rn(pr.w, pr.y);
        float pcy = __fadd_rn(pr.x, __fmul_rn(0.5f, ph));
        float pcx = __fadd_rn(pr.y, __fmul_rn(0.5f, pw));
        float4 dl = ((const float4*)deltas)[r];
        float d0 = __fmul_rn(dl.x, 0.1f);
        float d1 = __fmul_rn(dl.y, 0.1f);
        float d2 = __fmul_rn(dl.z, 0.2f);
        float d3 = __fmul_rn(dl.w, 0.2f);
        float cy = __fadd_rn(__fmul_rn(d0, ph), pcy);
        float cx = __fadd_rn(__fmul_rn(d1, pw), pcx);
        float hh = __fmul_rn(expf(d2), ph);
        float ww = __fmul_rn(expf(d3), pw);
        float h2 = __fmul_rn(hh, 0.5f);
        float w2 = __fmul_rn(ww, 0.5f);
        float y1 = fminf(fmaxf(__fsub_rn(cy, h2), 0.0f), 1.0f);
        float x1 = fminf(fmaxf(__fsub_rn(cx, w2), 0.0f), 1.0f);
        float y2 = fminf(fmaxf(__fadd_rn(cy, h2), 0.0f), 1.0f);
        float x2 = fminf(fmaxf(__fadd_rn(cx, w2), 0.0f), 1.0f);
        boxes[r] = make_float4(y1, x1, y2, x2);
    }
}

// ---------------------------------------------------------------------------
// Kernel 2: per-(b,c) sorted-scan greedy NMS. 256 threads.
// Dynamic sort size (512 when cnt<=512). Exact fallback bands unchanged.
// ---------------------------------------------------------------------------
__global__ __launch_bounds__(256) void k_nms(
    const float* __restrict__ labels, const unsigned char* __restrict__ bg,
    const float4* __restrict__ boxes, const int* __restrict__ cnt_g,
    const u64* __restrict__ cand_g,
    float* __restrict__ out_s, int* __restrict__ out_i)
{
    __shared__ u64 arr[CAND_CAP];
    __shared__ float4 sbox[CAND_CAP];
    __shared__ float ks[KK];
    __shared__ int   ki[KK];
    __shared__ int s_kept, s_cnt;

    int bc = blockIdx.x, tid = threadIdx.x;
    int b = bc / CC, c = bc - b * CC;
    const float4* bxb = boxes + (size_t)b * NN;

    int gcnt = cnt_g[bc * PADI];
    bool ovf = gcnt > CAND_CAP;
    int cnt0 = ovf ? 0 : gcnt;
    for (int i = tid; i < CAND_CAP; i += 256)
        arr[i] = (i < cnt0) ? cand_g[(size_t)bc * CAND_CAP + i] : 0ull;
    if (tid == 0) { s_kept = 0; s_cnt = cnt0; }
    __syncthreads();

    float4 kb = make_float4(0.f, 0.f, 0.f, 0.f);
    float  ka = 0.0f;
    float hi = ovf ? 1.0001f : T1;
    float bw = TIER_W;
    bool first = !ovf;

    while (true) {
        if (!first) {
            if (s_kept >= KK || hi <= 0.5f) break;
            float lo = fmaxf(hi - bw, 0.5f);
            if (tid == 0) s_cnt = 0;
            __syncthreads();
            const float* lab = labels + (size_t)b * NN * CC + c;
            const unsigned char* bgb = bg + (size_t)b * NN;
            for (int n = tid; n < NN; n += 256) {
                float v = lab[(size_t)n * CC];
                if (v > lo && v <= hi && v > 0.5f && !bgb[n]) {
                    int p = atomicAdd(&s_cnt, 1);
                    if (p < CAND_CAP) arr[p] = pack_cand(v, n);
                }
            }
            __syncthreads();
            if (s_cnt > CAND_CAP && bw > 1e-7f) {  // band overflow: shrink, retry
                bw *= 0.5f;
                __syncthreads();
                continue;
            }
            int c2 = min(s_cnt, CAND_CAP);
            for (int i = tid; i < CAND_CAP; i += 256)
                if (i >= c2) arr[i] = 0ull;
            hi = lo;
            bw = TIER_W;
            __syncthreads();
        }
        first = false;

        int cs = min(s_cnt, CAND_CAP);
        if (cs <= 512) bitonic_desc<512, 256>(arr, tid);   // uniform branch
        else           bitonic_desc<CAND_CAP, 256>(arr, tid);
        int cnt = cs;
        for (int i = tid; i < cnt; i += 256) {   // stage boxes, one gather
            int n = (int)(~(u32)arr[i]);
            if ((u32)n < (u32)NN) sbox[i] = bxb[n];   // guard: never faults
        }
        __syncthreads();

        if (tid < 64) {                          // wave 0: serial greedy scan
            int kept = s_kept;
            for (int i = 0; i < cnt; ++i) {
                u64 key = arr[i];
                float sc = __uint_as_float((u32)(key >> 32));
                int n = (int)(~(u32)key);
                float4 cb = sbox[i];
                float a1 = __fmul_rn(__fsub_rn(cb.z, cb.x), __fsub_rn(cb.w, cb.y));
                bool sup = false;
                if (tid < kept) {
                    float iy1 = fmaxf(kb.x, cb.x);
                    float ix1 = fmaxf(kb.y, cb.y);
                    float iy2 = fminf(kb.z, cb.z);
                    float ix2 = fminf(kb.w, cb.w);
                    float ih = fmaxf(__fsub_rn(iy2, iy1), 0.0f);
                    float iw = fmaxf(__fsub_rn(ix2, ix1), 0.0f);
                    float inter = __fmul_rn(ih, iw);
                    float den = __fadd_rn(__fsub_rn(__fadd_rn(ka, a1), inter), 1e-8f);
                    sup = __fdiv_rn(inter, den) > 0.5f;
                }
                if (__ballot(sup) == 0ull) {
                    if (tid == kept) { kb = cb; ka = a1; }
                    if (tid == 0)    { ks[kept] = sc; ki[kept] = n; }
                    ++kept;
                    if (kept == KK) break;
                }
            }
            if (tid == 0) s_kept = kept;
        }
        __syncthreads();
    }

    int kept = min(s_kept, KK);
    for (int k = tid; k < KK; k += 256) {
        out_s[(size_t)bc * KK + k] = (k < kept) ? ks[k] : 0.0f;
        out_i[(size_t)bc * KK + k] = (k < kept) ? ki[k] : 0;
    }
}

// ---------------------------------------------------------------------------
// Kernel 3a: per-(batch, 512-chunk) partial top-200. Grid = BB*8 blocks.
// Global top-200 of a batch is a subset of the union of chunk top-200s.
// ---------------------------------------------------------------------------
__global__ __launch_bounds__(256) void k_topk1(
    const float* __restrict__ nms_s, u64* __restrict__ topA)
{
    __shared__ u64 arr[512];
    int bchunk = blockIdx.x;
    int b = bchunk >> 3, ch = bchunk & 7;
    int tid = threadIdx.x;
    int base = ch * 512;
    for (int i = tid; i < 512; i += 256) {
        int fp = base + i;
        u64 v = 0ull;
        if (fp < CC * KK) {
            float s = nms_s[(size_t)b * CC * KK + fp];
            v = ((u64)__float_as_uint(s) << 32) | (u32)(~(u32)fp);
        }
        arr[i] = v;
    }
    __syncthreads();
    bitonic_desc<512, 256>(arr, tid);
    if (tid < MT) topA[(size_t)bchunk * MT + tid] = arr[tid];
}

// ---------------------------------------------------------------------------
// Kernel 3b: per-batch merge of 8x200 -> stable top-200 + output assembly.
// ---------------------------------------------------------------------------
__global__ __launch_bounds__(512) void k_topk2(
    const u64* __restrict__ topA, const int* __restrict__ nms_i,
    const float4* __restrict__ boxes, float* __restrict__ out)
{
    __shared__ u64 arr[2048];
    __shared__ int s_vc;
    int b = blockIdx.x, tid = threadIdx.x;
    for (int i = tid; i < 2048; i += 512)
        arr[i] = (i < 8 * MT) ? topA[(size_t)b * 8 * MT + i] : 0ull;
    if (tid == 0) s_vc = 0;
    __syncthreads();

    bitonic_desc<2048, 512>(arr, tid);

    if (tid < MT) {
        u64 key = arr[tid];
        float sc = __uint_as_float((u32)(key >> 32));
        int fp = (int)(~(u32)key);
        bool valid = sc > 0.0f;
        float4 bb = make_float4(0.f, 0.f, 0.f, 0.f);
        float cls = 0.0f;
        if (valid) {
            int aidx = nms_i[(size_t)b * CC * KK + fp];
            bb = boxes[(size_t)b * NN + aidx];
            cls = (float)(fp / KK);
        }
        ((float4*)out)[(size_t)b * MT + tid] = bb;
        out[(size_t)BB * MT * 4 + (size_t)b * MT + tid] = sc;
        out[(size_t)BB * MT * 5 + (size_t)b * MT + tid] = cls;
        if (valid) atomicAdd(&s_vc, 1);
    }
    __syncthreads();
    if (tid == 0) out[(size_t)BB * MT * 6 + b] = (float)s_vc;
}

// ---------------------------------------------------------------------------
extern "C" void kernel_launch(void* const* d_in, const int* in_sizes, int n_in,
                              void* d_out, int out_size, void* d_ws, size_t ws_size,
                              hipStream_t stream)
{
    const float* deltas = (const float*)d_in[0];
    const float* labels = (const float*)d_in[1];
    const float* priors = (const float*)d_in[2];
    float* out = (float*)d_out;

    char* ws = (char*)d_ws;
    size_t off = 0;
    float4* boxes = (float4*)(ws + off);            off += (size_t)NROWS * 16;
    unsigned char* bg = (unsigned char*)(ws + off); off += ((size_t)NROWS + 127) & ~127ull;
    int* cnt_g = (int*)(ws + off);                  off += (size_t)BB * CC * PADI * 4;
    u64* cand_g = (u64*)(ws + off);                 off += (size_t)BB * CC * CAND_CAP * 8;
    float* nms_s = (float*)(ws + off);              off += (size_t)BB * CC * KK * 4;
    int* nms_i = (int*)(ws + off);                  off += (size_t)BB * CC * KK * 4;
    u64* topA = (u64*)(ws + off);                   off += (size_t)BB * 8 * MT * 8;

    hipMemsetAsync(cnt_g, 0, (size_t)BB * CC * PADI * 4, stream);
    k_decode_filter<<<BB * RB, 128, 0, stream>>>(deltas, labels, priors,
                                                 boxes, bg, cnt_g, cand_g);
    k_nms<<<BB * CC, 256, 0, stream>>>(labels, bg, boxes, cnt_g, cand_g, nms_s, nms_i);
    k_topk1<<<BB * 8, 256, 0, stream>>>(nms_s, topA);
    k_topk2<<<BB, 512, 0, stream>>>(topA, nms_i, boxes, out);
}

// Round 8
// 185.291 us; speedup vs baseline: 17.6706x; 1.0063x over previous
//
#include <hip/hip_runtime.h>
#include <math.h>

#define BB 16
#define NN 24564
#define CC 81
#define KK 50
#define MT 200
#define NROWS (BB * NN)
#define PB 96                  // row-blocks per batch: ceil(24564/256)
#define CAND_CAP 1024          // per-(b,c) list capacity (mean ~485, sd ~22 -> 24 sigma)
#define T1 0.98f               // tier-1 score threshold
#define TIER_W 0.02f
#define PADI 32                // ints per counter slot (128B padding)
#define CHUNK 128              // k_nms box-staging chunk

typedef unsigned long long u64;
typedef unsigned int u32;

// 16B load with only 4B alignment guarantee (row stride 324B)
struct __attribute__((packed, aligned(4))) F4 { float x, y, z, w; };

__device__ __forceinline__ u64 pack_cand(float s, int n) {
    return ((u64)__float_as_uint(s) << 32) | (u32)(~(u32)n);
}

// descending bitonic sort of P u64 keys in LDS, NT threads
template <int P, int NT>
__device__ __forceinline__ void bitonic_desc(u64* a, int tid) {
    for (int k = 2; k <= P; k <<= 1) {
        for (int j = k >> 1; j > 0; j >>= 1) {
            for (int i = tid; i < P; i += NT) {
                int l = i ^ j;
                if (l > i) {
                    u64 x = a[i], y = a[l];
                    bool sw = (i & k) ? (x > y) : (x < y);
                    if (sw) { a[i] = y; a[l] = x; }
                }
            }
            __syncthreads();
        }
    }
}

// ---------------------------------------------------------------------------
// Kernel 1: fused decode + bg + candidate filter. 256 threads = 4 independent
// waves; 1 lane = 1 anchor row, streamed from global through L1 (no LDS
// staging -> occupancy no longer LDS-capped). Per-wave ballot masks + 81
// parallel lane-atomics; ranked fire-and-forget scatter re-reads values (L1).
// ---------------------------------------------------------------------------
__global__ __launch_bounds__(256) void k_decode_filter(
    const float* __restrict__ deltas, const float* __restrict__ labels,
    const float* __restrict__ priors, float4* __restrict__ boxes,
    unsigned char* __restrict__ bg, int* __restrict__ cnt_g,
    u64* __restrict__ cand_g)
{
    __shared__ u64 s_mask[4][CC];
    __shared__ int s_base[4][CC];

    int tid = threadIdx.x;
    int wv = tid >> 6, lane = tid & 63;
    int b = blockIdx.x / PB, blk = blockIdx.x - b * PB;
    int n = blk * 256 + wv * 64 + lane;
    bool inb = n < NN;

    size_t rowoff = ((size_t)b * NN + (inb ? n : 0)) * CC;
    float L0 = 0.0f, m = 0.0f;
    u64 win0 = 0; u32 win1 = 0;
    if (inb) {
        const F4* row4 = (const F4*)(labels + rowoff);
        L0 = labels[rowoff];
        m = L0;
        #pragma unroll 4
        for (int j = 0; j < 16; ++j) {           // classes 0..63
            F4 x = row4[j];
            m = fmaxf(m, fmaxf(fmaxf(x.x, x.y), fmaxf(x.z, x.w)));
            u64 bits = (u64)(x.x > T1) | ((u64)(x.y > T1) << 1)
                     | ((u64)(x.z > T1) << 2) | ((u64)(x.w > T1) << 3);
            win0 |= bits << (4 * j);
        }
        #pragma unroll
        for (int j = 16; j < 20; ++j) {          // classes 64..79
            F4 x = row4[j];
            m = fmaxf(m, fmaxf(fmaxf(x.x, x.y), fmaxf(x.z, x.w)));
            u32 bits = (u32)(x.x > T1) | ((u32)(x.y > T1) << 1)
                     | ((u32)(x.z > T1) << 2) | ((u32)(x.w > T1) << 3);
            win1 |= bits << (4 * (j - 16));
        }
        float l80 = labels[rowoff + 80];         // class 80
        m = fmaxf(m, l80);
        win1 |= (u32)(l80 > T1) << 16;
    }
    bool isbg = (L0 >= m);                       // argmax==0, first-index rule
    if (inb) bg[(size_t)b * NN + n] = isbg ? 1 : 0;
    if (isbg) { win0 = 0; win1 = 0; }            // !inb lanes already zero

    // phase 1: per-class ballots into per-wave LDS masks (wave-synchronous)
    #pragma unroll 1
    for (int c = 0; c < 64; ++c) {
        u64 mm = __ballot((win0 >> c) & 1);
        if (lane == 0) s_mask[wv][c] = mm;
    }
    #pragma unroll 1
    for (int c = 64; c < CC; ++c) {
        u64 mm = __ballot((win1 >> (c - 64)) & 1);
        if (lane == 0) s_mask[wv][c] = mm;
    }

    // phase 2: 81 concurrent slot allocations per wave (2 atomic instrs)
    {
        u64 mk = s_mask[wv][lane];
        int v2 = 0;
        if (mk) v2 = atomicAdd(&cnt_g[(b * CC + lane) * PADI], (int)__popcll(mk));
        s_base[wv][lane] = v2;
        int c3 = 64 + lane;
        if (c3 < CC) {
            u64 mk3 = s_mask[wv][c3];
            int v3 = 0;
            if (mk3) v3 = atomicAdd(&cnt_g[(b * CC + c3) * PADI], (int)__popcll(mk3));
            s_base[wv][c3] = v3;
        }
    }

    // phase 3: ranked fire-and-forget scatter (values re-read, L1-hot)
    u64 ltmask = (lane == 63) ? 0x7FFFFFFFFFFFFFFFull : ((1ull << lane) - 1ull);
    u64 w0 = win0;
    while (w0) {
        int c = __ffsll(w0) - 1; w0 &= w0 - 1;
        u64 mm = s_mask[wv][c];
        int p = s_base[wv][c] + (int)__popcll(mm & ltmask);
        if (p < CAND_CAP)
            cand_g[(size_t)(b * CC + c) * CAND_CAP + p] =
                pack_cand(labels[rowoff + c], n);
    }
    u32 w1 = win1;
    while (w1) {
        int j = __ffs(w1) - 1; w1 &= w1 - 1;
        int c = 64 + j;
        u64 mm = s_mask[wv][c];
        int p = s_base[wv][c] + (int)__popcll(mm & ltmask);
        if (p < CAND_CAP)
            cand_g[(size_t)(b * CC + c) * CAND_CAP + p] =
                pack_cand(labels[rowoff + c], n);
    }

    // box decode (exact numpy op order, FMA-free)
    if (inb) {
        size_t r = (size_t)b * NN + n;
        float4 pr = ((const float4*)priors)[n];
        float ph  = __fsub_rn(pr.z, pr.x);
        float pw  = __fsub_rn(pr.w, pr.y);
        float pcy = __fadd_rn(pr.x, __fmul_rn(0.5f, ph));
        float pcx = __fadd_rn(pr.y, __fmul_rn(0.5f, pw));
        float4 dl = ((const float4*)deltas)[r];
        float d0 = __fmul_rn(dl.x, 0.1f);
        float d1 = __fmul_rn(dl.y, 0.1f);
        float d2 = __fmul_rn(dl.z, 0.2f);
        float d3 = __fmul_rn(dl.w, 0.2f);
        float cy = __fadd_rn(__fmul_rn(d0, ph), pcy);
        float cx = __fadd_rn(__fmul_rn(d1, pw), pcx);
        float hh = __fmul_rn(expf(d2), ph);
        float ww = __fmul_rn(expf(d3), pw);
        float h2 = __fmul_rn(hh, 0.5f);
        float w2 = __fmul_rn(ww, 0.5f);
        float y1 = fminf(fmaxf(__fsub_rn(cy, h2), 0.0f), 1.0f);
        float x1 = fminf(fmaxf(__fsub_rn(cx, w2), 0.0f), 1.0f);
        float y2 = fminf(fmaxf(__fadd_rn(cy, h2), 0.0f), 1.0f);
        float x2 = fminf(fmaxf(__fadd_rn(cx, w2), 0.0f), 1.0f);
        boxes[r] = make_float4(y1, x1, y2, x2);
    }
}

// ---------------------------------------------------------------------------
// Kernel 2: per-(b,c) sorted-scan greedy NMS. 256 threads.
// Chunked box staging (128 at a time; scan needs ~51) -> LDS 10.5 KB.
// Dynamic sort size; exact fallback bands unchanged.
// ---------------------------------------------------------------------------
__global__ __launch_bounds__(256) void k_nms(
    const float* __restrict__ labels, const unsigned char* __restrict__ bg,
    const float4* __restrict__ boxes, const int* __restrict__ cnt_g,
    const u64* __restrict__ cand_g,
    float* __restrict__ out_s, int* __restrict__ out_i)
{
    __shared__ u64 arr[CAND_CAP];
    __shared__ float4 sbox[CHUNK];
    __shared__ float ks[KK];
    __shared__ int   ki[KK];
    __shared__ int s_kept, s_cnt;

    int bc = blockIdx.x, tid = threadIdx.x;
    int b = bc / CC, c = bc - b * CC;
    const float4* bxb = boxes + (size_t)b * NN;

    int gcnt = cnt_g[bc * PADI];
    bool ovf = gcnt > CAND_CAP;
    int cnt0 = ovf ? 0 : gcnt;
    for (int i = tid; i < CAND_CAP; i += 256)
        arr[i] = (i < cnt0) ? cand_g[(size_t)bc * CAND_CAP + i] : 0ull;
    if (tid == 0) { s_kept = 0; s_cnt = cnt0; }
    __syncthreads();

    float4 kb = make_float4(0.f, 0.f, 0.f, 0.f);
    float  ka = 0.0f;
    float hi = ovf ? 1.0001f : T1;
    float bw = TIER_W;
    bool first = !ovf;

    while (true) {
        if (!first) {
            if (s_kept >= KK || hi <= 0.5f) break;
            float lo = fmaxf(hi - bw, 0.5f);
            if (tid == 0) s_cnt = 0;
            __syncthreads();
            const float* lab = labels + (size_t)b * NN * CC + c;
            const unsigned char* bgb = bg + (size_t)b * NN;
            for (int n = tid; n < NN; n += 256) {
                float v = lab[(size_t)n * CC];
                if (v > lo && v <= hi && v > 0.5f && !bgb[n]) {
                    int p = atomicAdd(&s_cnt, 1);
                    if (p < CAND_CAP) arr[p] = pack_cand(v, n);
                }
            }
            __syncthreads();
            if (s_cnt > CAND_CAP && bw > 1e-7f) {  // band overflow: shrink, retry
                bw *= 0.5f;
                __syncthreads();
                continue;
            }
            int c2 = min(s_cnt, CAND_CAP);
            for (int i = tid; i < CAND_CAP; i += 256)
                if (i >= c2) arr[i] = 0ull;
            hi = lo;
            bw = TIER_W;
            __syncthreads();
        }
        first = false;

        int cs = min(s_cnt, CAND_CAP);
        if (cs <= 512) bitonic_desc<512, 256>(arr, tid);   // uniform branch
        else           bitonic_desc<CAND_CAP, 256>(arr, tid);

        // chunked stage + scan: most blocks finish in the first 128
        for (int ch0 = 0; ch0 < cs; ch0 += CHUNK) {
            if (s_kept >= KK) break;                       // uniform (post-sync)
            int che = min(ch0 + CHUNK, cs);
            for (int i = ch0 + tid; i < che; i += 256) {
                int n = (int)(~(u32)arr[i]);
                if ((u32)n < (u32)NN) sbox[i - ch0] = bxb[n];  // guarded
            }
            __syncthreads();
            if (tid < 64) {                    // wave 0: serial greedy scan
                int kept = s_kept;
                for (int i = ch0; i < che; ++i) {
                    u64 key = arr[i];
                    float sc = __uint_as_float((u32)(key >> 32));
                    int n = (int)(~(u32)key);
                    float4 cb = sbox[i - ch0];
                    float a1 = __fmul_rn(__fsub_rn(cb.z, cb.x), __fsub_rn(cb.w, cb.y));
                    bool sup = false;
                    if (tid < kept) {
                        float iy1 = fmaxf(kb.x, cb.x);
                        float ix1 = fmaxf(kb.y, cb.y);
                        float iy2 = fminf(kb.z, cb.z);
                        float ix2 = fminf(kb.w, cb.w);
                        float ih = fmaxf(__fsub_rn(iy2, iy1), 0.0f);
                        float iw = fmaxf(__fsub_rn(ix2, ix1), 0.0f);
                        float inter = __fmul_rn(ih, iw);
                        float den = __fadd_rn(__fsub_rn(__fadd_rn(ka, a1), inter), 1e-8f);
                        sup = __fdiv_rn(inter, den) > 0.5f;
                    }
                    if (__ballot(sup) == 0ull) {
                        if (tid == kept) { kb = cb; ka = a1; }
                        if (tid == 0)    { ks[kept] = sc; ki[kept] = n; }
                        ++kept;
                        if (kept == KK) break;
                    }
                }
                if (tid == 0) s_kept = kept;
            }
            __syncthreads();
        }
    }

    int kept = min(s_kept, KK);
    for (int k = tid; k < KK; k += 256) {
        out_s[(size_t)bc * KK + k] = (k < kept) ? ks[k] : 0.0f;
        out_i[(size_t)bc * KK + k] = (k < kept) ? ki[k] : 0;
    }
}

// ---------------------------------------------------------------------------
// Kernel 3a: per-(batch, 512-chunk) partial top-200. Grid = BB*8 blocks.
// ---------------------------------------------------------------------------
__global__ __launch_bounds__(256) void k_topk1(
    const float* __restrict__ nms_s, u64* __restrict__ topA)
{
    __shared__ u64 arr[512];
    int bchunk = blockIdx.x;
    int b = bchunk >> 3, ch = bchunk & 7;
    int tid = threadIdx.x;
    int base = ch * 512;
    for (int i = tid; i < 512; i += 256) {
        int fp = base + i;
        u64 v = 0ull;
        if (fp < CC * KK) {
            float s = nms_s[(size_t)b * CC * KK + fp];
            v = ((u64)__float_as_uint(s) << 32) | (u32)(~(u32)fp);
        }
        arr[i] = v;
    }
    __syncthreads();
    bitonic_desc<512, 256>(arr, tid);
    if (tid < MT) topA[(size_t)bchunk * MT + tid] = arr[tid];
}

// ---------------------------------------------------------------------------
// Kernel 3b: per-batch merge of 8x200 -> stable top-200 + output assembly.
// ---------------------------------------------------------------------------
__global__ __launch_bounds__(512) void k_topk2(
    const u64* __restrict__ topA, const int* __restrict__ nms_i,
    const float4* __restrict__ boxes, float* __restrict__ out)
{
    __shared__ u64 arr[2048];
    __shared__ int s_vc;
    int b = blockIdx.x, tid = threadIdx.x;
    for (int i = tid; i < 2048; i += 512)
        arr[i] = (i < 8 * MT) ? topA[(size_t)b * 8 * MT + i] : 0ull;
    if (tid == 0) s_vc = 0;
    __syncthreads();

    bitonic_desc<2048, 512>(arr, tid);

    if (tid < MT) {
        u64 key = arr[tid];
        float sc = __uint_as_float((u32)(key >> 32));
        int fp = (int)(~(u32)key);
        bool valid = sc > 0.0f;
        float4 bb = make_float4(0.f, 0.f, 0.f, 0.f);
        float cls = 0.0f;
        if (valid) {
            int aidx = nms_i[(size_t)b * CC * KK + fp];
            bb = boxes[(size_t)b * NN + aidx];
            cls = (float)(fp / KK);
        }
        ((float4*)out)[(size_t)b * MT + tid] = bb;
        out[(size_t)BB * MT * 4 + (size_t)b * MT + tid] = sc;
        out[(size_t)BB * MT * 5 + (size_t)b * MT + tid] = cls;
        if (valid) atomicAdd(&s_vc, 1);
    }
    __syncthreads();
    if (tid == 0) out[(size_t)BB * MT * 6 + b] = (float)s_vc;
}

// ---------------------------------------------------------------------------
extern "C" void kernel_launch(void* const* d_in, const int* in_sizes, int n_in,
                              void* d_out, int out_size, void* d_ws, size_t ws_size,
                              hipStream_t stream)
{
    const float* deltas = (const float*)d_in[0];
    const float* labels = (const float*)d_in[1];
    const float* priors = (const float*)d_in[2];
    float* out = (float*)d_out;

    char* ws = (char*)d_ws;
    size_t off = 0;
    float4* boxes = (float4*)(ws + off);            off += (size_t)NROWS * 16;
    unsigned char* bg = (unsigned char*)(ws + off); off += ((size_t)NROWS + 127) & ~127ull;
    int* cnt_g = (int*)(ws + off);                  off += (size_t)BB * CC * PADI * 4;
    u64* cand_g = (u64*)(ws + off);                 off += (size_t)BB * CC * CAND_CAP * 8;
    float* nms_s = (float*)(ws + off);              off += (size_t)BB * CC * KK * 4;
    int* nms_i = (int*)(ws + off);                  off += (size_t)BB * CC * KK * 4;
    u64* topA = (u64*)(ws + off);                   off += (size_t)BB * 8 * MT * 8;

    hipMemsetAsync(cnt_g, 0, (size_t)BB * CC * PADI * 4, stream);
    k_decode_filter<<<BB * PB, 256, 0, stream>>>(deltas, labels, priors,
                                                 boxes, bg, cnt_g, cand_g);
    k_nms<<<BB * CC, 256, 0, stream>>>(labels, bg, boxes, cnt_g, cand_g, nms_s, nms_i);
    k_topk1<<<BB * 8, 256, 0, stream>>>(nms_s, topA);
    k_topk2<<<BB, 512, 0, stream>>>(topA, nms_i, boxes, out);
}